// Round 1
// baseline (719.526 us; speedup 1.0000x reference)
//
#include <hip/hip_runtime.h>
#include <stdint.h>

typedef unsigned int u32;
typedef uint16_t u16;

#define EPSV 1e-12f

__device__ __forceinline__ u16 f2bf(float f) {
    u32 u = __float_as_uint(f);
    return (u16)((u + 0x7fffu + ((u >> 16) & 1u)) >> 16);
}
__device__ __forceinline__ float bf2f(u32 s) { return __uint_as_float(s << 16); }

// ---------------------------------------------------------------------------
// K1: edge MLP -> sigmoid weights; also accumulate raw degree + CSR counts
// ---------------------------------------------------------------------------
__global__ __launch_bounds__(256) void k_edge(
    const float* __restrict__ ea, const float* __restrict__ We1,
    const float* __restrict__ be1, const float* __restrict__ We2,
    const float* __restrict__ be2, const int* __restrict__ src,
    const int* __restrict__ dst, float* __restrict__ ew,
    float* __restrict__ deg, int* __restrict__ cnt, int E)
{
    __shared__ float w1t[32 * 16];  // transposed [j][k]
    __shared__ float b1s[32];
    __shared__ float w2s[32];
    __shared__ float b2s;
    int tid = threadIdx.x;
    for (int i = tid; i < 512; i += 256) {
        int k = i >> 5, j = i & 31;
        w1t[j * 16 + k] = We1[i];
    }
    if (tid < 32) { b1s[tid] = be1[tid]; w2s[tid] = We2[tid]; }
    if (tid == 0) b2s = be2[0];
    __syncthreads();

    int e = blockIdx.x * 256 + tid;
    if (e >= E) return;

    const float4* pa = (const float4*)(ea + (size_t)e * 16);
    float4 A0 = pa[0], A1 = pa[1], A2 = pa[2], A3 = pa[3];
    float av[16] = {A0.x, A0.y, A0.z, A0.w, A1.x, A1.y, A1.z, A1.w,
                    A2.x, A2.y, A2.z, A2.w, A3.x, A3.y, A3.z, A3.w};

    float acc = b2s;
#pragma unroll
    for (int j = 0; j < 32; ++j) {
        const float4* wr = (const float4*)(w1t + j * 16);
        float4 q0 = wr[0], q1 = wr[1], q2 = wr[2], q3 = wr[3];
        float s = b1s[j];
        s += av[0] * q0.x + av[1] * q0.y + av[2] * q0.z + av[3] * q0.w;
        s += av[4] * q1.x + av[5] * q1.y + av[6] * q1.z + av[7] * q1.w;
        s += av[8] * q2.x + av[9] * q2.y + av[10] * q2.z + av[11] * q2.w;
        s += av[12] * q3.x + av[13] * q3.y + av[14] * q3.z + av[15] * q3.w;
        acc += fmaxf(s, 0.f) * w2s[j];
    }
    float sig = 1.f / (1.f + __expf(-acc));
    ew[e] = sig;
    int s_ = src[e], d_ = dst[e];
    atomicAdd(&deg[s_], sig);
    atomicAdd(&deg[d_], sig);
    atomicAdd(&cnt[s_], 1);
    atomicAdd(&cnt[d_], 1);
}

// ---------------------------------------------------------------------------
// K2: single-block exclusive scan of counts -> rowptr; also dinv = rsqrt(deg)
// ---------------------------------------------------------------------------
__global__ __launch_bounds__(1024) void k_scan(
    const int* __restrict__ cnt, int* __restrict__ rowptr,
    const float* __restrict__ deg, float* __restrict__ dinv, int n)
{
    int tid = threadIdx.x, lane = tid & 63, w = tid >> 6;
    for (int i = tid; i < n; i += 1024) dinv[i] = rsqrtf(deg[i] + EPSV);

    __shared__ int wsum[16];
    int running = 0;
    for (int base = 0; base < n; base += 1024) {
        int x = (base + tid < n) ? cnt[base + tid] : 0;
        int v = x;
#pragma unroll
        for (int d = 1; d < 64; d <<= 1) {
            int t = __shfl_up(v, d);
            if (lane >= d) v += t;
        }
        if (lane == 63) wsum[w] = v;
        __syncthreads();
        if (w == 0) {
            int s = (lane < 16) ? wsum[lane] : 0;
#pragma unroll
            for (int d = 1; d < 16; d <<= 1) {
                int t = __shfl_up(s, d);
                if (lane >= d) s += t;
            }
            if (lane < 16) wsum[lane] = s;
        }
        __syncthreads();
        int waveoff = (w == 0) ? 0 : wsum[w - 1];
        if (base + tid < n) rowptr[base + tid] = running + waveoff + v - x;
        running += wsum[15];
        __syncthreads();
    }
    if (tid == 0) rowptr[n] = running;
}

// ---------------------------------------------------------------------------
// K3: fill CSR (cols + normalized vals)
// ---------------------------------------------------------------------------
__global__ __launch_bounds__(256) void k_fill(
    const int* __restrict__ src, const int* __restrict__ dst,
    const float* __restrict__ ew, const float* __restrict__ dinv,
    const int* __restrict__ rowptr, int* __restrict__ fillc,
    int* __restrict__ colv, float* __restrict__ valv, int E)
{
    int idx = blockIdx.x * 256 + threadIdx.x;
    if (idx >= 2 * E) return;
    int e = (idx < E) ? idx : idx - E;
    int r = (idx < E) ? src[e] : dst[e];
    int c = (idx < E) ? dst[e] : src[e];
    float v = ew[e] * dinv[r] * dinv[c];
    int pos = rowptr[r] + atomicAdd(&fillc[r], 1);
    colv[pos] = c;
    valv[pos] = v;
}

// ---------------------------------------------------------------------------
// K4: XX = H @ [W1 | W2]  (fp32 compute, bf16 store), 64 rows x 256 cols/block
// ---------------------------------------------------------------------------
__global__ __launch_bounds__(256) void k_gemm1(
    const float* __restrict__ H, const float* __restrict__ W1,
    const float* __restrict__ W2, u16* __restrict__ XXb, int n)
{
    __shared__ float Asm[64 * 132];   // padded stride
    __shared__ float Bsm[16 * 256];
    int tid = threadIdx.x;
    int r0blk = blockIdx.x * 64;

    for (int idx = tid; idx < 64 * 128; idx += 256) {
        int r = idx >> 7, k = idx & 127;
        int gi = r0blk + r;
        Asm[r * 132 + k] = (gi < n) ? H[(size_t)gi * 128 + k] : 0.f;
    }

    float acc[4][16];
#pragma unroll
    for (int i = 0; i < 4; i++)
#pragma unroll
        for (int j = 0; j < 16; j++) acc[i][j] = 0.f;

    int c0 = (tid & 15) * 4;       // cols: c0 + 64*j + {0..3}, j=0..3
    int r0 = (tid >> 4) * 4;

    for (int k0 = 0; k0 < 128; k0 += 16) {
        __syncthreads();
        for (int idx = tid; idx < 16 * 256; idx += 256) {
            int kk = idx >> 8, c = idx & 255;
            Bsm[idx] = (c < 128) ? W1[(size_t)(k0 + kk) * 128 + c]
                                 : W2[(size_t)(k0 + kk) * 128 + (c - 128)];
        }
        __syncthreads();
#pragma unroll
        for (int kk = 0; kk < 16; kk++) {
            float a_[4];
#pragma unroll
            for (int i = 0; i < 4; i++) a_[i] = Asm[(r0 + i) * 132 + k0 + kk];
#pragma unroll
            for (int j = 0; j < 4; j++) {
                float4 b = *(const float4*)(Bsm + kk * 256 + c0 + 64 * j);
#pragma unroll
                for (int i = 0; i < 4; i++) {
                    acc[i][j * 4 + 0] += a_[i] * b.x;
                    acc[i][j * 4 + 1] += a_[i] * b.y;
                    acc[i][j * 4 + 2] += a_[i] * b.z;
                    acc[i][j * 4 + 3] += a_[i] * b.w;
                }
            }
        }
    }

#pragma unroll
    for (int i = 0; i < 4; i++) {
        int gi = r0blk + r0 + i;
        if (gi >= n) continue;
#pragma unroll
        for (int j = 0; j < 4; j++) {
            u32 lo = f2bf(acc[i][j * 4 + 0]) | ((u32)f2bf(acc[i][j * 4 + 1]) << 16);
            u32 hi = f2bf(acc[i][j * 4 + 2]) | ((u32)f2bf(acc[i][j * 4 + 3]) << 16);
            *(uint2*)(XXb + (size_t)gi * 256 + c0 + 64 * j) = make_uint2(lo, hi);
        }
    }
}

// ---------------------------------------------------------------------------
// K5: Y = A @ XX  (256 cols, bf16 in/out, fp32 acc). One wave per row.
// ---------------------------------------------------------------------------
__global__ __launch_bounds__(256) void k_spmm256(
    const int* __restrict__ rowptr, const int* __restrict__ colv,
    const float* __restrict__ valv, const u16* __restrict__ Xb,
    u16* __restrict__ Yb, int n)
{
    int lane = threadIdx.x & 63;
    int row = blockIdx.x * 4 + (threadIdx.x >> 6);
    if (row >= n) return;
    int s = rowptr[row], e = rowptr[row + 1];
    float a0 = 0.f, a1 = 0.f, a2 = 0.f, a3 = 0.f;
    for (int base = s; base < e; base += 64) {
        int p = base + lane;
        int c = (p < e) ? colv[p] : 0;
        float v = (p < e) ? valv[p] : 0.f;
        int m = min(64, e - base);
        for (int j = 0; j < m; j++) {
            int cj = __shfl(c, j);
            float vj = __shfl(v, j);
            uint2 d = *(const uint2*)(Xb + (size_t)cj * 256 + lane * 4);
            a0 += vj * bf2f(d.x & 0xffffu);
            a1 += vj * bf2f(d.x >> 16);
            a2 += vj * bf2f(d.y & 0xffffu);
            a3 += vj * bf2f(d.y >> 16);
        }
    }
    u32 lo = f2bf(a0) | ((u32)f2bf(a1) << 16);
    u32 hi = f2bf(a2) | ((u32)f2bf(a3) << 16);
    *(uint2*)(Yb + (size_t)row * 256 + lane * 4) = make_uint2(lo, hi);
}

// ---------------------------------------------------------------------------
// K6: h2 = A @ Y[:,128:256]  (128 cols). One wave per row.
// ---------------------------------------------------------------------------
__global__ __launch_bounds__(256) void k_spmm128(
    const int* __restrict__ rowptr, const int* __restrict__ colv,
    const float* __restrict__ valv, const u16* __restrict__ Yb,
    u16* __restrict__ h2b, int n)
{
    int lane = threadIdx.x & 63;
    int row = blockIdx.x * 4 + (threadIdx.x >> 6);
    if (row >= n) return;
    int s = rowptr[row], e = rowptr[row + 1];
    float a0 = 0.f, a1 = 0.f;
    for (int base = s; base < e; base += 64) {
        int p = base + lane;
        int c = (p < e) ? colv[p] : 0;
        float v = (p < e) ? valv[p] : 0.f;
        int m = min(64, e - base);
        for (int j = 0; j < m; j++) {
            int cj = __shfl(c, j);
            float vj = __shfl(v, j);
            u32 d = *(const u32*)(Yb + (size_t)cj * 256 + 128 + lane * 2);
            a0 += vj * bf2f(d & 0xffffu);
            a1 += vj * bf2f(d >> 16);
        }
    }
    *(u32*)(h2b + (size_t)row * 128 + lane * 2) =
        f2bf(a0) | ((u32)f2bf(a1) << 16);
}

// ---------------------------------------------------------------------------
// K7: out = relu([gc*h1 + (1-gc)*h2, H] @ W_up + b_up)
// ---------------------------------------------------------------------------
__global__ __launch_bounds__(256) void k_final(
    const u16* __restrict__ Yb, const u16* __restrict__ h2b,
    const float* __restrict__ H, const float* __restrict__ Wup,
    const float* __restrict__ bup, const float* __restrict__ gp,
    float* __restrict__ out, int n)
{
    __shared__ u16 Asm[64 * 264];   // bf16, padded stride 264
    __shared__ float Bsm[32 * 128];
    int tid = threadIdx.x;
    int r0blk = blockIdx.x * 64;
    float gc = fminf(fmaxf(gp[0], 0.f), 1.f);
    float omg = 1.f - gc;

    for (int idx = tid; idx < 64 * 32; idx += 256) {
        int r = idx >> 5, kq = idx & 31;
        int gi = r0blk + r;
        uint2 y = make_uint2(0u, 0u), h2 = make_uint2(0u, 0u);
        float4 hf = make_float4(0.f, 0.f, 0.f, 0.f);
        if (gi < n) {
            y = *(const uint2*)(Yb + (size_t)gi * 256 + kq * 4);
            h2 = *(const uint2*)(h2b + (size_t)gi * 128 + kq * 4);
            hf = *(const float4*)(H + (size_t)gi * 128 + kq * 4);
        }
        float a0 = gc * bf2f(y.x & 0xffffu) + omg * bf2f(h2.x & 0xffffu);
        float a1 = gc * bf2f(y.x >> 16) + omg * bf2f(h2.x >> 16);
        float a2 = gc * bf2f(y.y & 0xffffu) + omg * bf2f(h2.y & 0xffffu);
        float a3 = gc * bf2f(y.y >> 16) + omg * bf2f(h2.y >> 16);
        *(uint2*)(Asm + (size_t)r * 264 + kq * 4) =
            make_uint2(f2bf(a0) | ((u32)f2bf(a1) << 16),
                       f2bf(a2) | ((u32)f2bf(a3) << 16));
        *(uint2*)(Asm + (size_t)r * 264 + 128 + kq * 4) =
            make_uint2(f2bf(hf.x) | ((u32)f2bf(hf.y) << 16),
                       f2bf(hf.z) | ((u32)f2bf(hf.w) << 16));
    }

    float acc[4][8];
#pragma unroll
    for (int i = 0; i < 4; i++)
#pragma unroll
        for (int j = 0; j < 8; j++) acc[i][j] = 0.f;

    int c0 = (tid & 15) * 4;    // cols: c0 + 64*j + {0..3}, j=0..1
    int r0 = (tid >> 4) * 4;

    for (int k0 = 0; k0 < 256; k0 += 32) {
        __syncthreads();
        for (int idx = tid; idx < 1024; idx += 256) {
            int kk = idx >> 5, cq = idx & 31;
            *(float4*)(Bsm + kk * 128 + cq * 4) =
                *(const float4*)(Wup + (size_t)(k0 + kk) * 128 + cq * 4);
        }
        __syncthreads();
#pragma unroll
        for (int kk = 0; kk < 32; kk++) {
            float a_[4];
#pragma unroll
            for (int i = 0; i < 4; i++) a_[i] = bf2f(Asm[(r0 + i) * 264 + k0 + kk]);
#pragma unroll
            for (int j = 0; j < 2; j++) {
                float4 b = *(const float4*)(Bsm + kk * 128 + c0 + 64 * j);
#pragma unroll
                for (int i = 0; i < 4; i++) {
                    acc[i][j * 4 + 0] += a_[i] * b.x;
                    acc[i][j * 4 + 1] += a_[i] * b.y;
                    acc[i][j * 4 + 2] += a_[i] * b.z;
                    acc[i][j * 4 + 3] += a_[i] * b.w;
                }
            }
        }
    }

#pragma unroll
    for (int i = 0; i < 4; i++) {
        int gi = r0blk + r0 + i;
        if (gi >= n) continue;
#pragma unroll
        for (int j = 0; j < 2; j++) {
            int cb = c0 + 64 * j;
            float4 o;
            o.x = fmaxf(acc[i][j * 4 + 0] + bup[cb + 0], 0.f);
            o.y = fmaxf(acc[i][j * 4 + 1] + bup[cb + 1], 0.f);
            o.z = fmaxf(acc[i][j * 4 + 2] + bup[cb + 2], 0.f);
            o.w = fmaxf(acc[i][j * 4 + 3] + bup[cb + 3], 0.f);
            *(float4*)(out + (size_t)gi * 128 + cb) = o;
        }
    }
}

// ---------------------------------------------------------------------------
extern "C" void kernel_launch(void* const* d_in, const int* in_sizes, int n_in,
                              void* d_out, int out_size, void* d_ws,
                              size_t ws_size, hipStream_t stream)
{
    (void)n_in; (void)out_size; (void)ws_size;
    const float* H   = (const float*)d_in[0];
    const int*   ei  = (const int*)d_in[1];
    const float* ea  = (const float*)d_in[2];
    const float* W1  = (const float*)d_in[3];
    const float* W2  = (const float*)d_in[4];
    const float* We1 = (const float*)d_in[5];
    const float* be1 = (const float*)d_in[6];
    const float* We2 = (const float*)d_in[7];
    const float* be2 = (const float*)d_in[8];
    const float* g   = (const float*)d_in[9];
    const float* Wup = (const float*)d_in[10];
    const float* bup = (const float*)d_in[11];

    int n = in_sizes[0] / 128;
    int E = in_sizes[1] / 2;
    const int* src = ei;
    const int* dst = ei + E;
    float* out = (float*)d_out;

    char* wsp = (char*)d_ws;
    auto alloc = [&](size_t bytes) -> char* {
        char* p = wsp;
        wsp += (bytes + 255) & ~(size_t)255;
        return p;
    };
    float* ew     = (float*)alloc((size_t)E * 4);
    float* deg    = (float*)alloc((size_t)n * 4);
    int*   cnt    = (int*)alloc((size_t)n * 4);
    int*   fillc  = (int*)alloc((size_t)n * 4);
    int*   rowptr = (int*)alloc((size_t)(n + 1) * 4);
    float* dinv   = (float*)alloc((size_t)n * 4);
    int*   colv   = (int*)alloc((size_t)2 * E * 4);
    float* valv   = (float*)alloc((size_t)2 * E * 4);
    u16*   XXb    = (u16*)alloc((size_t)n * 256 * 2);
    u16*   Yb     = (u16*)alloc((size_t)n * 256 * 2);
    u16*   h2b    = (u16*)alloc((size_t)n * 128 * 2);

    hipMemsetAsync(deg, 0, (size_t)n * 4, stream);
    hipMemsetAsync(cnt, 0, (size_t)n * 4, stream);
    hipMemsetAsync(fillc, 0, (size_t)n * 4, stream);

    k_edge<<<(E + 255) / 256, 256, 0, stream>>>(ea, We1, be1, We2, be2, src,
                                                dst, ew, deg, cnt, E);
    k_scan<<<1, 1024, 0, stream>>>(cnt, rowptr, deg, dinv, n);
    k_fill<<<(2 * E + 255) / 256, 256, 0, stream>>>(src, dst, ew, dinv, rowptr,
                                                    fillc, colv, valv, E);
    k_gemm1<<<(n + 63) / 64, 256, 0, stream>>>(H, W1, W2, XXb, n);
    k_spmm256<<<(n + 3) / 4, 256, 0, stream>>>(rowptr, colv, valv, XXb, Yb, n);
    k_spmm128<<<(n + 3) / 4, 256, 0, stream>>>(rowptr, colv, valv, Yb, h2b, n);
    k_final<<<(n + 63) / 64, 256, 0, stream>>>(Yb, h2b, H, Wup, bup, g, out, n);
}

// Round 2
// 532.300 us; speedup vs baseline: 1.3517x; 1.3517x over previous
//
#include <hip/hip_runtime.h>
#include <stdint.h>

typedef unsigned int u32;
typedef uint16_t u16;

#define EPSV 1e-12f
#define NB 64            // histogram blocks
#define BINS 12800       // bins per pass (51.2 KB LDS)

__device__ __forceinline__ u16 f2bf(float f) {
    u32 u = __float_as_uint(f);
    return (u16)((u + 0x7fffu + ((u >> 16) & 1u)) >> 16);
}
__device__ __forceinline__ float bf2f(u32 s) { return __uint_as_float(s << 16); }

// ---------------------------------------------------------------------------
// K1: edge MLP -> sigmoid weights (no atomics)
// ---------------------------------------------------------------------------
__global__ __launch_bounds__(256) void k_edge(
    const float* __restrict__ ea, const float* __restrict__ We1,
    const float* __restrict__ be1, const float* __restrict__ We2,
    const float* __restrict__ be2, float* __restrict__ ew, int E)
{
    __shared__ float w1t[32 * 16];  // transposed [j][k]
    __shared__ float b1s[32];
    __shared__ float w2s[32];
    __shared__ float b2s;
    int tid = threadIdx.x;
    for (int i = tid; i < 512; i += 256) {
        int k = i >> 5, j = i & 31;
        w1t[j * 16 + k] = We1[i];
    }
    if (tid < 32) { b1s[tid] = be1[tid]; w2s[tid] = We2[tid]; }
    if (tid == 0) b2s = be2[0];
    __syncthreads();

    int e = blockIdx.x * 256 + tid;
    if (e >= E) return;

    const float4* pa = (const float4*)(ea + (size_t)e * 16);
    float4 A0 = pa[0], A1 = pa[1], A2 = pa[2], A3 = pa[3];
    float av[16] = {A0.x, A0.y, A0.z, A0.w, A1.x, A1.y, A1.z, A1.w,
                    A2.x, A2.y, A2.z, A2.w, A3.x, A3.y, A3.z, A3.w};

    float acc = b2s;
#pragma unroll
    for (int j = 0; j < 32; ++j) {
        const float4* wr = (const float4*)(w1t + j * 16);
        float4 q0 = wr[0], q1 = wr[1], q2 = wr[2], q3 = wr[3];
        float s = b1s[j];
        s += av[0] * q0.x + av[1] * q0.y + av[2] * q0.z + av[3] * q0.w;
        s += av[4] * q1.x + av[5] * q1.y + av[6] * q1.z + av[7] * q1.w;
        s += av[8] * q2.x + av[9] * q2.y + av[10] * q2.z + av[11] * q2.w;
        s += av[12] * q3.x + av[13] * q3.y + av[14] * q3.z + av[15] * q3.w;
        acc += fmaxf(s, 0.f) * w2s[j];
    }
    ew[e] = 1.f / (1.f + __expf(-acc));
}

// ---------------------------------------------------------------------------
// K2: per-block LDS histograms of row ids. hb[b*n + r] = count in block b.
// ---------------------------------------------------------------------------
__global__ __launch_bounds__(1024) void k_hist(
    const int* __restrict__ src, const int* __restrict__ dst,
    int* __restrict__ hb, int E, int n)
{
    __shared__ int h[BINS];
    int b = blockIdx.x;
    int E2 = 2 * E;
    int per = (E2 + NB - 1) / NB;
    int lo_e = b * per, hi_e = min(E2, lo_e + per);
    int npass = (n + BINS - 1) / BINS;

    for (int pass = 0; pass < npass; ++pass) {
        int lo = pass * BINS, hi = min(n, lo + BINS);
        for (int i = threadIdx.x; i < BINS; i += 1024) h[i] = 0;
        __syncthreads();
        for (int idx = lo_e + threadIdx.x; idx < hi_e; idx += 1024) {
            int r = (idx < E) ? src[idx] : dst[idx - E];
            if (r >= lo && r < hi) atomicAdd(&h[r - lo], 1);
        }
        __syncthreads();
        for (int i = threadIdx.x; i < hi - lo; i += 1024)
            hb[(size_t)b * n + lo + i] = h[i];
        __syncthreads();
    }
}

// ---------------------------------------------------------------------------
// K3: tot[r] = sum_b hb[b][r]
// ---------------------------------------------------------------------------
__global__ __launch_bounds__(256) void k_rowsum(
    const int* __restrict__ hb, int* __restrict__ tot, int n)
{
    int r = blockIdx.x * 256 + threadIdx.x;
    if (r >= n) return;
    int s = 0;
#pragma unroll 8
    for (int b = 0; b < NB; ++b) s += hb[(size_t)b * n + r];
    tot[r] = s;
}

// ---------------------------------------------------------------------------
// K4: single-block exclusive scan: tot -> rowptr
// ---------------------------------------------------------------------------
__global__ __launch_bounds__(1024) void k_scan(
    const int* __restrict__ tot, int* __restrict__ rowptr, int n)
{
    int tid = threadIdx.x, lane = tid & 63, w = tid >> 6;
    __shared__ int wsum[16];
    int running = 0;
    for (int base = 0; base < n; base += 1024) {
        int x = (base + tid < n) ? tot[base + tid] : 0;
        int v = x;
#pragma unroll
        for (int d = 1; d < 64; d <<= 1) {
            int t = __shfl_up(v, d);
            if (lane >= d) v += t;
        }
        if (lane == 63) wsum[w] = v;
        __syncthreads();
        if (w == 0) {
            int s = (lane < 16) ? wsum[lane] : 0;
#pragma unroll
            for (int d = 1; d < 16; d <<= 1) {
                int t = __shfl_up(s, d);
                if (lane >= d) s += t;
            }
            if (lane < 16) wsum[lane] = s;
        }
        __syncthreads();
        int waveoff = (w == 0) ? 0 : wsum[w - 1];
        if (base + tid < n) rowptr[base + tid] = running + waveoff + v - x;
        running += wsum[15];
        __syncthreads();
    }
    if (tid == 0) rowptr[n] = running;
}

// ---------------------------------------------------------------------------
// K5: hb[b][r] <- rowptr[r] + prefix_{b'<b} hb[b'][r]   (in place)
// ---------------------------------------------------------------------------
__global__ __launch_bounds__(256) void k_off(
    const int* __restrict__ rowptr, int* __restrict__ hb, int n)
{
    int r = blockIdx.x * 256 + threadIdx.x;
    if (r >= n) return;
    int run = rowptr[r];
    for (int b = 0; b < NB; ++b) {
        int t = hb[(size_t)b * n + r];
        hb[(size_t)b * n + r] = run;
        run += t;
    }
}

// ---------------------------------------------------------------------------
// K6: fill CSR. Positions via LDS atomicAdd on preloaded per-block offsets.
//     cva[p] = {col, ew-bits}
// ---------------------------------------------------------------------------
__global__ __launch_bounds__(1024) void k_fill(
    const int* __restrict__ src, const int* __restrict__ dst,
    const float* __restrict__ ew, int* __restrict__ hb,
    uint2* __restrict__ cva, int E, int n)
{
    __shared__ int hofs[BINS];
    int b = blockIdx.x;
    int E2 = 2 * E;
    int per = (E2 + NB - 1) / NB;
    int lo_e = b * per, hi_e = min(E2, lo_e + per);
    int npass = (n + BINS - 1) / BINS;

    for (int pass = 0; pass < npass; ++pass) {
        int lo = pass * BINS, hi = min(n, lo + BINS);
        for (int i = threadIdx.x; i < hi - lo; i += 1024)
            hofs[i] = hb[(size_t)b * n + lo + i];
        __syncthreads();
        for (int idx = lo_e + threadIdx.x; idx < hi_e; idx += 1024) {
            int e = (idx < E) ? idx : idx - E;
            int r, c;
            if (idx < E) { r = src[e]; c = dst[e]; }
            else         { r = dst[e]; c = src[e]; }
            if (r >= lo && r < hi) {
                int pos = atomicAdd(&hofs[r - lo], 1);
                cva[pos] = make_uint2((u32)c, __float_as_uint(ew[e]));
            }
        }
        __syncthreads();
    }
}

// ---------------------------------------------------------------------------
// K7: deg -> dinv (wave per row)
// ---------------------------------------------------------------------------
__global__ __launch_bounds__(256) void k_deg(
    const int* __restrict__ rowptr, const uint2* __restrict__ cva,
    float* __restrict__ dinv, int n)
{
    int lane = threadIdx.x & 63;
    int row = blockIdx.x * 4 + (threadIdx.x >> 6);
    if (row >= n) return;
    int s = rowptr[row], e = rowptr[row + 1];
    float sum = 0.f;
    for (int p = s + lane; p < e; p += 64) sum += __uint_as_float(cva[p].y);
#pragma unroll
    for (int d = 1; d < 64; d <<= 1) sum += __shfl_xor(sum, d);
    if (lane == 0) dinv[row] = rsqrtf(sum + EPSV);
}

// ---------------------------------------------------------------------------
// K8: normalize vals in place: v *= dinv[r]*dinv[c]
// ---------------------------------------------------------------------------
__global__ __launch_bounds__(256) void k_norm(
    const int* __restrict__ rowptr, uint2* __restrict__ cva,
    const float* __restrict__ dinv, int n)
{
    int lane = threadIdx.x & 63;
    int row = blockIdx.x * 4 + (threadIdx.x >> 6);
    if (row >= n) return;
    int s = rowptr[row], e = rowptr[row + 1];
    float dr = dinv[row];
    for (int p = s + lane; p < e; p += 64) {
        uint2 cv = cva[p];
        float v = __uint_as_float(cv.y) * dr * dinv[cv.x];
        cva[p] = make_uint2(cv.x, __float_as_uint(v));
    }
}

// ---------------------------------------------------------------------------
// K9: XX = H @ [W1 | W2]  (fp32 compute, bf16 store)
// ---------------------------------------------------------------------------
__global__ __launch_bounds__(256) void k_gemm1(
    const float* __restrict__ H, const float* __restrict__ W1,
    const float* __restrict__ W2, u16* __restrict__ XXb, int n)
{
    __shared__ float Asm[64 * 132];
    __shared__ float Bsm[16 * 256];
    int tid = threadIdx.x;
    int r0blk = blockIdx.x * 64;

    for (int idx = tid; idx < 64 * 128; idx += 256) {
        int r = idx >> 7, k = idx & 127;
        int gi = r0blk + r;
        Asm[r * 132 + k] = (gi < n) ? H[(size_t)gi * 128 + k] : 0.f;
    }

    float acc[4][16];
#pragma unroll
    for (int i = 0; i < 4; i++)
#pragma unroll
        for (int j = 0; j < 16; j++) acc[i][j] = 0.f;

    int c0 = (tid & 15) * 4;
    int r0 = (tid >> 4) * 4;

    for (int k0 = 0; k0 < 128; k0 += 16) {
        __syncthreads();
        for (int idx = tid; idx < 16 * 256; idx += 256) {
            int kk = idx >> 8, c = idx & 255;
            Bsm[idx] = (c < 128) ? W1[(size_t)(k0 + kk) * 128 + c]
                                 : W2[(size_t)(k0 + kk) * 128 + (c - 128)];
        }
        __syncthreads();
#pragma unroll
        for (int kk = 0; kk < 16; kk++) {
            float a_[4];
#pragma unroll
            for (int i = 0; i < 4; i++) a_[i] = Asm[(r0 + i) * 132 + k0 + kk];
#pragma unroll
            for (int j = 0; j < 4; j++) {
                float4 b = *(const float4*)(Bsm + kk * 256 + c0 + 64 * j);
#pragma unroll
                for (int i = 0; i < 4; i++) {
                    acc[i][j * 4 + 0] += a_[i] * b.x;
                    acc[i][j * 4 + 1] += a_[i] * b.y;
                    acc[i][j * 4 + 2] += a_[i] * b.z;
                    acc[i][j * 4 + 3] += a_[i] * b.w;
                }
            }
        }
    }

#pragma unroll
    for (int i = 0; i < 4; i++) {
        int gi = r0blk + r0 + i;
        if (gi >= n) continue;
#pragma unroll
        for (int j = 0; j < 4; j++) {
            u32 lo = f2bf(acc[i][j * 4 + 0]) | ((u32)f2bf(acc[i][j * 4 + 1]) << 16);
            u32 hi = f2bf(acc[i][j * 4 + 2]) | ((u32)f2bf(acc[i][j * 4 + 3]) << 16);
            *(uint2*)(XXb + (size_t)gi * 256 + c0 + 64 * j) = make_uint2(lo, hi);
        }
    }
}

// ---------------------------------------------------------------------------
// K10: Y = A @ XX (256 cols). Wave per row, neighbor broadcast, unroll 4.
// ---------------------------------------------------------------------------
__global__ __launch_bounds__(256) void k_spmm256(
    const int* __restrict__ rowptr, const uint2* __restrict__ cva,
    const u16* __restrict__ Xb, u16* __restrict__ Yb, int n)
{
    int lane = threadIdx.x & 63;
    int row = blockIdx.x * 4 + (threadIdx.x >> 6);
    if (row >= n) return;
    int s = rowptr[row], e = rowptr[row + 1];
    float a0 = 0.f, a1 = 0.f, a2 = 0.f, a3 = 0.f;

    for (int base = s; base < e; base += 64) {
        int p = base + lane;
        int c = 0; float w = 0.f;
        if (p < e) { uint2 cv = cva[p]; c = (int)cv.x; w = __uint_as_float(cv.y); }
        int m = min(64, e - base);
#define STEP256(J)                                                         \
        {                                                                  \
            int cj = __shfl(c, (J));                                       \
            float wj = __shfl(w, (J));                                     \
            uint2 d = *(const uint2*)(Xb + (size_t)cj * 256 + lane * 4);   \
            a0 += wj * bf2f(d.x & 0xffffu);                                \
            a1 += wj * bf2f(d.x >> 16);                                    \
            a2 += wj * bf2f(d.y & 0xffffu);                                \
            a3 += wj * bf2f(d.y >> 16);                                    \
        }
        int j = 0;
        for (; j + 4 <= m; j += 4) { STEP256(j) STEP256(j + 1) STEP256(j + 2) STEP256(j + 3) }
        for (; j < m; ++j) { STEP256(j) }
#undef STEP256
    }
    u32 lo = f2bf(a0) | ((u32)f2bf(a1) << 16);
    u32 hi = f2bf(a2) | ((u32)f2bf(a3) << 16);
    *(uint2*)(Yb + (size_t)row * 256 + lane * 4) = make_uint2(lo, hi);
}

// ---------------------------------------------------------------------------
// K11: h2 = A @ Y[:,128:256]. Wave per row, 2 neighbors across wave halves.
// ---------------------------------------------------------------------------
__global__ __launch_bounds__(256) void k_spmm128(
    const int* __restrict__ rowptr, const uint2* __restrict__ cva,
    const u16* __restrict__ Yb, u16* __restrict__ h2b, int n)
{
    int lane = threadIdx.x & 63;
    int l = lane & 31, half = lane >> 5;
    int row = blockIdx.x * 4 + (threadIdx.x >> 6);
    if (row >= n) return;
    int s = rowptr[row], e = rowptr[row + 1];
    float a0 = 0.f, a1 = 0.f, a2 = 0.f, a3 = 0.f;

    for (int base = s; base < e; base += 64) {
        int p = base + lane;
        int c = 0; float w = 0.f;
        if (p < e) { uint2 cv = cva[p]; c = (int)cv.x; w = __uint_as_float(cv.y); }
        int m = min(64, e - base);
        int j = 0;
        for (; j + 2 <= m; j += 2) {
            int jj = j + half;
            int cj = __shfl(c, jj);
            float wj = __shfl(w, jj);
            uint2 d = *(const uint2*)(Yb + (size_t)cj * 256 + 128 + l * 4);
            a0 += wj * bf2f(d.x & 0xffffu);
            a1 += wj * bf2f(d.x >> 16);
            a2 += wj * bf2f(d.y & 0xffffu);
            a3 += wj * bf2f(d.y >> 16);
        }
        if (j < m) {  // odd tail: neighbor j handled by half 0 only
            int cj = __shfl(c, j);
            float wj = half ? 0.f : __shfl(w, j);
            uint2 d = *(const uint2*)(Yb + (size_t)cj * 256 + 128 + l * 4);
            a0 += wj * bf2f(d.x & 0xffffu);
            a1 += wj * bf2f(d.x >> 16);
            a2 += wj * bf2f(d.y & 0xffffu);
            a3 += wj * bf2f(d.y >> 16);
        }
    }
    a0 += __shfl_xor(a0, 32);
    a1 += __shfl_xor(a1, 32);
    a2 += __shfl_xor(a2, 32);
    a3 += __shfl_xor(a3, 32);
    if (half == 0) {
        u32 lo = f2bf(a0) | ((u32)f2bf(a1) << 16);
        u32 hi = f2bf(a2) | ((u32)f2bf(a3) << 16);
        *(uint2*)(h2b + (size_t)row * 128 + l * 4) = make_uint2(lo, hi);
    }
}

// ---------------------------------------------------------------------------
// K12: out = relu([gc*h1 + (1-gc)*h2, H] @ W_up + b_up)
// ---------------------------------------------------------------------------
__global__ __launch_bounds__(256) void k_final(
    const u16* __restrict__ Yb, const u16* __restrict__ h2b,
    const float* __restrict__ H, const float* __restrict__ Wup,
    const float* __restrict__ bup, const float* __restrict__ gp,
    float* __restrict__ out, int n)
{
    __shared__ u16 Asm[64 * 264];
    __shared__ float Bsm[32 * 128];
    int tid = threadIdx.x;
    int r0blk = blockIdx.x * 64;
    float gc = fminf(fmaxf(gp[0], 0.f), 1.f);
    float omg = 1.f - gc;

    for (int idx = tid; idx < 64 * 32; idx += 256) {
        int r = idx >> 5, kq = idx & 31;
        int gi = r0blk + r;
        uint2 y = make_uint2(0u, 0u), h2 = make_uint2(0u, 0u);
        float4 hf = make_float4(0.f, 0.f, 0.f, 0.f);
        if (gi < n) {
            y = *(const uint2*)(Yb + (size_t)gi * 256 + kq * 4);
            h2 = *(const uint2*)(h2b + (size_t)gi * 128 + kq * 4);
            hf = *(const float4*)(H + (size_t)gi * 128 + kq * 4);
        }
        float a0 = gc * bf2f(y.x & 0xffffu) + omg * bf2f(h2.x & 0xffffu);
        float a1 = gc * bf2f(y.x >> 16) + omg * bf2f(h2.x >> 16);
        float a2 = gc * bf2f(y.y & 0xffffu) + omg * bf2f(h2.y & 0xffffu);
        float a3 = gc * bf2f(y.y >> 16) + omg * bf2f(h2.y >> 16);
        *(uint2*)(Asm + (size_t)r * 264 + kq * 4) =
            make_uint2(f2bf(a0) | ((u32)f2bf(a1) << 16),
                       f2bf(a2) | ((u32)f2bf(a3) << 16));
        *(uint2*)(Asm + (size_t)r * 264 + 128 + kq * 4) =
            make_uint2(f2bf(hf.x) | ((u32)f2bf(hf.y) << 16),
                       f2bf(hf.z) | ((u32)f2bf(hf.w) << 16));
    }

    float acc[4][8];
#pragma unroll
    for (int i = 0; i < 4; i++)
#pragma unroll
        for (int j = 0; j < 8; j++) acc[i][j] = 0.f;

    int c0 = (tid & 15) * 4;
    int r0 = (tid >> 4) * 4;

    for (int k0 = 0; k0 < 256; k0 += 32) {
        __syncthreads();
        for (int idx = tid; idx < 1024; idx += 256) {
            int kk = idx >> 5, cq = idx & 31;
            *(float4*)(Bsm + kk * 128 + cq * 4) =
                *(const float4*)(Wup + (size_t)(k0 + kk) * 128 + cq * 4);
        }
        __syncthreads();
#pragma unroll
        for (int kk = 0; kk < 32; kk++) {
            float a_[4];
#pragma unroll
            for (int i = 0; i < 4; i++) a_[i] = bf2f(Asm[(r0 + i) * 264 + k0 + kk]);
#pragma unroll
            for (int j = 0; j < 2; j++) {
                float4 b = *(const float4*)(Bsm + kk * 128 + c0 + 64 * j);
#pragma unroll
                for (int i = 0; i < 4; i++) {
                    acc[i][j * 4 + 0] += a_[i] * b.x;
                    acc[i][j * 4 + 1] += a_[i] * b.y;
                    acc[i][j * 4 + 2] += a_[i] * b.z;
                    acc[i][j * 4 + 3] += a_[i] * b.w;
                }
            }
        }
    }

#pragma unroll
    for (int i = 0; i < 4; i++) {
        int gi = r0blk + r0 + i;
        if (gi >= n) continue;
#pragma unroll
        for (int j = 0; j < 2; j++) {
            int cb = c0 + 64 * j;
            float4 o;
            o.x = fmaxf(acc[i][j * 4 + 0] + bup[cb + 0], 0.f);
            o.y = fmaxf(acc[i][j * 4 + 1] + bup[cb + 1], 0.f);
            o.z = fmaxf(acc[i][j * 4 + 2] + bup[cb + 2], 0.f);
            o.w = fmaxf(acc[i][j * 4 + 3] + bup[cb + 3], 0.f);
            *(float4*)(out + (size_t)gi * 128 + cb) = o;
        }
    }
}

// ---------------------------------------------------------------------------
extern "C" void kernel_launch(void* const* d_in, const int* in_sizes, int n_in,
                              void* d_out, int out_size, void* d_ws,
                              size_t ws_size, hipStream_t stream)
{
    (void)n_in; (void)out_size; (void)ws_size;
    const float* H   = (const float*)d_in[0];
    const int*   ei  = (const int*)d_in[1];
    const float* ea  = (const float*)d_in[2];
    const float* W1  = (const float*)d_in[3];
    const float* W2  = (const float*)d_in[4];
    const float* We1 = (const float*)d_in[5];
    const float* be1 = (const float*)d_in[6];
    const float* We2 = (const float*)d_in[7];
    const float* be2 = (const float*)d_in[8];
    const float* g   = (const float*)d_in[9];
    const float* Wup = (const float*)d_in[10];
    const float* bup = (const float*)d_in[11];

    int n = in_sizes[0] / 128;
    int E = in_sizes[1] / 2;
    const int* src = ei;
    const int* dst = ei + E;
    float* out = (float*)d_out;

    char* wsp = (char*)d_ws;
    auto alloc = [&](size_t bytes) -> char* {
        char* p = wsp;
        wsp += (bytes + 255) & ~(size_t)255;
        return p;
    };
    float* ew     = (float*)alloc((size_t)E * 4);
    int*   tot    = (int*)alloc((size_t)n * 4);
    int*   rowptr = (int*)alloc((size_t)(n + 1) * 4);
    float* dinv   = (float*)alloc((size_t)n * 4);
    uint2* cva    = (uint2*)alloc((size_t)2 * E * 8);
    u16*   XXb    = (u16*)alloc((size_t)n * 256 * 2);   // hb aliases this
    u16*   Yb     = (u16*)alloc((size_t)n * 256 * 2);
    u16*   h2b    = (u16*)alloc((size_t)n * 128 * 2);
    int*   hb     = (int*)XXb;   // NB*n*4 = 12.8MB <= 25.6MB, dead before k_gemm1

    k_edge<<<(E + 255) / 256, 256, 0, stream>>>(ea, We1, be1, We2, be2, ew, E);
    k_hist<<<NB, 1024, 0, stream>>>(src, dst, hb, E, n);
    k_rowsum<<<(n + 255) / 256, 256, 0, stream>>>(hb, tot, n);
    k_scan<<<1, 1024, 0, stream>>>(tot, rowptr, n);
    k_off<<<(n + 255) / 256, 256, 0, stream>>>(rowptr, hb, n);
    k_fill<<<NB, 1024, 0, stream>>>(src, dst, ew, hb, cva, E, n);
    k_deg<<<(n + 3) / 4, 256, 0, stream>>>(rowptr, cva, dinv, n);
    k_norm<<<(n + 3) / 4, 256, 0, stream>>>(rowptr, cva, dinv, n);
    k_gemm1<<<(n + 63) / 64, 256, 0, stream>>>(H, W1, W2, XXb, n);
    k_spmm256<<<(n + 3) / 4, 256, 0, stream>>>(rowptr, cva, XXb, Yb, n);
    k_spmm128<<<(n + 3) / 4, 256, 0, stream>>>(rowptr, cva, Yb, h2b, n);
    k_final<<<(n + 63) / 64, 256, 0, stream>>>(Yb, h2b, H, Wup, bup, g, out, n);
}

// Round 3
// 417.904 us; speedup vs baseline: 1.7218x; 1.2737x over previous
//
#include <hip/hip_runtime.h>
#include <stdint.h>

typedef unsigned int u32;
typedef uint16_t u16;
typedef __attribute__((ext_vector_type(8))) short bf16x8;
typedef __attribute__((ext_vector_type(4))) float f32x4;

#define EPSV 1e-12f
#define NB 64            // histogram blocks
#define BINS 12800       // bins per pass (51.2 KB LDS)

__device__ __forceinline__ u16 f2bf(float f) {
    u32 u = __float_as_uint(f);
    return (u16)((u + 0x7fffu + ((u >> 16) & 1u)) >> 16);
}
__device__ __forceinline__ float bf2f(u32 s) { return __uint_as_float(s << 16); }

// ---------------------------------------------------------------------------
// K0: precompute transposed bf16 weights: Wtc[c][k] (c<128:W1, else W2),
//     Wtu[c][k] = Wup[k][c]
// ---------------------------------------------------------------------------
__global__ __launch_bounds__(256) void k_prep(
    const float* __restrict__ W1, const float* __restrict__ W2,
    const float* __restrict__ Wup, u16* __restrict__ Wtc,
    u16* __restrict__ Wtu)
{
    int gid = blockIdx.x * 256 + threadIdx.x;
    if (gid < 32768) {
        int c = gid >> 7, k = gid & 127;
        float v = (c < 128) ? W1[k * 128 + c] : W2[k * 128 + (c - 128)];
        Wtc[gid] = f2bf(v);
    } else {
        int g = gid - 32768;      // c*256 + k
        int c = g >> 8, k = g & 255;
        Wtu[g] = f2bf(Wup[k * 128 + c]);
    }
}

// ---------------------------------------------------------------------------
// K1: edge MLP -> sigmoid weights (no atomics)
// ---------------------------------------------------------------------------
__global__ __launch_bounds__(256) void k_edge(
    const float* __restrict__ ea, const float* __restrict__ We1,
    const float* __restrict__ be1, const float* __restrict__ We2,
    const float* __restrict__ be2, float* __restrict__ ew, int E)
{
    __shared__ float w1t[32 * 16];
    __shared__ float b1s[32];
    __shared__ float w2s[32];
    __shared__ float b2s;
    int tid = threadIdx.x;
    for (int i = tid; i < 512; i += 256) {
        int k = i >> 5, j = i & 31;
        w1t[j * 16 + k] = We1[i];
    }
    if (tid < 32) { b1s[tid] = be1[tid]; w2s[tid] = We2[tid]; }
    if (tid == 0) b2s = be2[0];
    __syncthreads();

    int e = blockIdx.x * 256 + tid;
    if (e >= E) return;

    const float4* pa = (const float4*)(ea + (size_t)e * 16);
    float4 A0 = pa[0], A1 = pa[1], A2 = pa[2], A3 = pa[3];
    float av[16] = {A0.x, A0.y, A0.z, A0.w, A1.x, A1.y, A1.z, A1.w,
                    A2.x, A2.y, A2.z, A2.w, A3.x, A3.y, A3.z, A3.w};

    float acc = b2s;
#pragma unroll
    for (int j = 0; j < 32; ++j) {
        const float4* wr = (const float4*)(w1t + j * 16);
        float4 q0 = wr[0], q1 = wr[1], q2 = wr[2], q3 = wr[3];
        float s = b1s[j];
        s += av[0] * q0.x + av[1] * q0.y + av[2] * q0.z + av[3] * q0.w;
        s += av[4] * q1.x + av[5] * q1.y + av[6] * q1.z + av[7] * q1.w;
        s += av[8] * q2.x + av[9] * q2.y + av[10] * q2.z + av[11] * q2.w;
        s += av[12] * q3.x + av[13] * q3.y + av[14] * q3.z + av[15] * q3.w;
        acc += fmaxf(s, 0.f) * w2s[j];
    }
    ew[e] = 1.f / (1.f + __expf(-acc));
}

// ---------------------------------------------------------------------------
// K2: per-block LDS histograms of row ids
// ---------------------------------------------------------------------------
__global__ __launch_bounds__(1024) void k_hist(
    const int* __restrict__ src, const int* __restrict__ dst,
    int* __restrict__ hb, int E, int n)
{
    __shared__ int h[BINS];
    int b = blockIdx.x;
    int E2 = 2 * E;
    int per = (E2 + NB - 1) / NB;
    int lo_e = b * per, hi_e = min(E2, lo_e + per);
    int npass = (n + BINS - 1) / BINS;

    for (int pass = 0; pass < npass; ++pass) {
        int lo = pass * BINS, hi = min(n, lo + BINS);
        for (int i = threadIdx.x; i < BINS; i += 1024) h[i] = 0;
        __syncthreads();
        for (int idx = lo_e + threadIdx.x; idx < hi_e; idx += 1024) {
            int r = (idx < E) ? src[idx] : dst[idx - E];
            if (r >= lo && r < hi) atomicAdd(&h[r - lo], 1);
        }
        __syncthreads();
        for (int i = threadIdx.x; i < hi - lo; i += 1024)
            hb[(size_t)b * n + lo + i] = h[i];
        __syncthreads();
    }
}

// ---------------------------------------------------------------------------
// K3: tot[r] = sum_b hb[b][r]
// ---------------------------------------------------------------------------
__global__ __launch_bounds__(256) void k_rowsum(
    const int* __restrict__ hb, int* __restrict__ tot, int n)
{
    int r = blockIdx.x * 256 + threadIdx.x;
    if (r >= n) return;
    int s = 0;
#pragma unroll 8
    for (int b = 0; b < NB; ++b) s += hb[(size_t)b * n + r];
    tot[r] = s;
}

// ---------------------------------------------------------------------------
// K4: single-block exclusive scan: tot -> rowptr
// ---------------------------------------------------------------------------
__global__ __launch_bounds__(1024) void k_scan(
    const int* __restrict__ tot, int* __restrict__ rowptr, int n)
{
    int tid = threadIdx.x, lane = tid & 63, w = tid >> 6;
    __shared__ int wsum[16];
    int running = 0;
    for (int base = 0; base < n; base += 1024) {
        int x = (base + tid < n) ? tot[base + tid] : 0;
        int v = x;
#pragma unroll
        for (int d = 1; d < 64; d <<= 1) {
            int t = __shfl_up(v, d);
            if (lane >= d) v += t;
        }
        if (lane == 63) wsum[w] = v;
        __syncthreads();
        if (w == 0) {
            int s = (lane < 16) ? wsum[lane] : 0;
#pragma unroll
            for (int d = 1; d < 16; d <<= 1) {
                int t = __shfl_up(s, d);
                if (lane >= d) s += t;
            }
            if (lane < 16) wsum[lane] = s;
        }
        __syncthreads();
        int waveoff = (w == 0) ? 0 : wsum[w - 1];
        if (base + tid < n) rowptr[base + tid] = running + waveoff + v - x;
        running += wsum[15];
        __syncthreads();
    }
    if (tid == 0) rowptr[n] = running;
}

// ---------------------------------------------------------------------------
// K5: hb[b][r] <- rowptr[r] + prefix_{b'<b} hb[b'][r]
// ---------------------------------------------------------------------------
__global__ __launch_bounds__(256) void k_off(
    const int* __restrict__ rowptr, int* __restrict__ hb, int n)
{
    int r = blockIdx.x * 256 + threadIdx.x;
    if (r >= n) return;
    int run = rowptr[r];
    for (int b = 0; b < NB; ++b) {
        int t = hb[(size_t)b * n + r];
        hb[(size_t)b * n + r] = run;
        run += t;
    }
}

// ---------------------------------------------------------------------------
// K6: fill CSR. Positions via LDS atomicAdd on preloaded per-block offsets.
// ---------------------------------------------------------------------------
__global__ __launch_bounds__(1024) void k_fill(
    const int* __restrict__ src, const int* __restrict__ dst,
    const float* __restrict__ ew, int* __restrict__ hb,
    uint2* __restrict__ cva, int E, int n)
{
    __shared__ int hofs[BINS];
    int b = blockIdx.x;
    int E2 = 2 * E;
    int per = (E2 + NB - 1) / NB;
    int lo_e = b * per, hi_e = min(E2, lo_e + per);
    int npass = (n + BINS - 1) / BINS;

    for (int pass = 0; pass < npass; ++pass) {
        int lo = pass * BINS, hi = min(n, lo + BINS);
        for (int i = threadIdx.x; i < hi - lo; i += 1024)
            hofs[i] = hb[(size_t)b * n + lo + i];
        __syncthreads();
        for (int idx = lo_e + threadIdx.x; idx < hi_e; idx += 1024) {
            int e = (idx < E) ? idx : idx - E;
            int r, c;
            if (idx < E) { r = src[e]; c = dst[e]; }
            else         { r = dst[e]; c = src[e]; }
            if (r >= lo && r < hi) {
                int pos = atomicAdd(&hofs[r - lo], 1);
                cva[pos] = make_uint2((u32)c, __float_as_uint(ew[e]));
            }
        }
        __syncthreads();
    }
}

// ---------------------------------------------------------------------------
// K7: deg -> dinv (wave per row)
// ---------------------------------------------------------------------------
__global__ __launch_bounds__(256) void k_deg(
    const int* __restrict__ rowptr, const uint2* __restrict__ cva,
    float* __restrict__ dinv, int n)
{
    int lane = threadIdx.x & 63;
    int row = blockIdx.x * 4 + (threadIdx.x >> 6);
    if (row >= n) return;
    int s = rowptr[row], e = rowptr[row + 1];
    float sum = 0.f;
    for (int p = s + lane; p < e; p += 64) sum += __uint_as_float(cva[p].y);
#pragma unroll
    for (int d = 1; d < 64; d <<= 1) sum += __shfl_xor(sum, d);
    if (lane == 0) dinv[row] = rsqrtf(sum + EPSV);
}

// ---------------------------------------------------------------------------
// K8: normalize vals in place: v *= dinv[r]*dinv[c]
// ---------------------------------------------------------------------------
__global__ __launch_bounds__(256) void k_norm(
    const int* __restrict__ rowptr, uint2* __restrict__ cva,
    const float* __restrict__ dinv, int n)
{
    int lane = threadIdx.x & 63;
    int row = blockIdx.x * 4 + (threadIdx.x >> 6);
    if (row >= n) return;
    int s = rowptr[row], e = rowptr[row + 1];
    float dr = dinv[row];
    for (int p = s + lane; p < e; p += 64) {
        uint2 cv = cva[p];
        float v = __uint_as_float(cv.y) * dr * dinv[cv.x];
        cva[p] = make_uint2(cv.x, __float_as_uint(v));
    }
}

// ---------------------------------------------------------------------------
// K9: XX = H @ [W1|W2] via MFMA bf16. Block: 64 rows x 256 cols, 4 waves.
//     A staged in LDS bf16 with 16B-slot XOR swizzle; B from global Wtc.
// ---------------------------------------------------------------------------
__global__ __launch_bounds__(256) void k_gemm1(
    const float* __restrict__ H, const u16* __restrict__ Wtc,
    u16* __restrict__ XXb, int n)
{
    __shared__ __align__(16) u16 Asm[64 * 128];
    int tid = threadIdx.x;
    int r0blk = blockIdx.x * 64;

#pragma unroll
    for (int it = 0; it < 4; ++it) {
        int sidx = tid + it * 256;           // 64 rows x 16 slots
        int row = sidx >> 4, slot = sidx & 15;
        int gi = r0blk + row;
        float4 f0 = make_float4(0.f, 0.f, 0.f, 0.f), f1 = f0;
        if (gi < n) {
            const float4* p = (const float4*)(H + (size_t)gi * 128 + slot * 8);
            f0 = p[0]; f1 = p[1];
        }
        uint4 w;
        w.x = f2bf(f0.x) | ((u32)f2bf(f0.y) << 16);
        w.y = f2bf(f0.z) | ((u32)f2bf(f0.w) << 16);
        w.z = f2bf(f1.x) | ((u32)f2bf(f1.y) << 16);
        w.w = f2bf(f1.z) | ((u32)f2bf(f1.w) << 16);
        ((uint4*)Asm)[row * 16 + (slot ^ (row & 7))] = w;
    }
    __syncthreads();

    int wv = tid >> 6, lane = tid & 63;
    int l15 = lane & 15, lg = lane >> 4;
    f32x4 acc[4][4] = {};
    const u16* Wb = Wtc + (size_t)(wv * 64) * 128;

#pragma unroll
    for (int ks = 0; ks < 4; ++ks) {
        bf16x8 bfr[4];
#pragma unroll
        for (int nt = 0; nt < 4; ++nt)
            bfr[nt] = *(const bf16x8*)(Wb + (size_t)(nt * 16 + l15) * 128 +
                                       ks * 32 + lg * 8);
        bf16x8 afr[4];
#pragma unroll
        for (int mt = 0; mt < 4; ++mt) {
            int row = mt * 16 + l15;
            int slot = ks * 4 + lg;
            afr[mt] = *(const bf16x8*)(Asm + row * 128 + (slot ^ (row & 7)) * 8);
        }
#pragma unroll
        for (int mt = 0; mt < 4; ++mt)
#pragma unroll
            for (int nt = 0; nt < 4; ++nt)
                acc[mt][nt] = __builtin_amdgcn_mfma_f32_16x16x32_bf16(
                    afr[mt], bfr[nt], acc[mt][nt], 0, 0, 0);
    }

#pragma unroll
    for (int mt = 0; mt < 4; ++mt)
#pragma unroll
        for (int r = 0; r < 4; ++r) {
            int gi = r0blk + mt * 16 + lg * 4 + r;
            if (gi >= n) continue;
#pragma unroll
            for (int nt = 0; nt < 4; ++nt)
                XXb[(size_t)gi * 256 + wv * 64 + nt * 16 + l15] =
                    f2bf(acc[mt][nt][r]);
        }
}

// ---------------------------------------------------------------------------
// K10: Y = A @ XX (256 cols). Wave per row, neighbor broadcast, unroll 4.
// ---------------------------------------------------------------------------
__global__ __launch_bounds__(256) void k_spmm256(
    const int* __restrict__ rowptr, const uint2* __restrict__ cva,
    const u16* __restrict__ Xb, u16* __restrict__ Yb, int n)
{
    int lane = threadIdx.x & 63;
    int row = blockIdx.x * 4 + (threadIdx.x >> 6);
    if (row >= n) return;
    int s = rowptr[row], e = rowptr[row + 1];
    float a0 = 0.f, a1 = 0.f, a2 = 0.f, a3 = 0.f;

    for (int base = s; base < e; base += 64) {
        int p = base + lane;
        int c = 0; float w = 0.f;
        if (p < e) { uint2 cv = cva[p]; c = (int)cv.x; w = __uint_as_float(cv.y); }
        int m = min(64, e - base);
#define STEP256(J)                                                         \
        {                                                                  \
            int cj = __shfl(c, (J));                                       \
            float wj = __shfl(w, (J));                                     \
            uint2 d = *(const uint2*)(Xb + (size_t)cj * 256 + lane * 4);   \
            a0 += wj * bf2f(d.x & 0xffffu);                                \
            a1 += wj * bf2f(d.x >> 16);                                    \
            a2 += wj * bf2f(d.y & 0xffffu);                                \
            a3 += wj * bf2f(d.y >> 16);                                    \
        }
        int j = 0;
        for (; j + 4 <= m; j += 4) { STEP256(j) STEP256(j + 1) STEP256(j + 2) STEP256(j + 3) }
        for (; j < m; ++j) { STEP256(j) }
#undef STEP256
    }
    u32 lo = f2bf(a0) | ((u32)f2bf(a1) << 16);
    u32 hi = f2bf(a2) | ((u32)f2bf(a3) << 16);
    *(uint2*)(Yb + (size_t)row * 256 + lane * 4) = make_uint2(lo, hi);
}

// ---------------------------------------------------------------------------
// K11: h2 = A @ Y[:,128:256]. Wave per row, 2 neighbors across wave halves.
// ---------------------------------------------------------------------------
__global__ __launch_bounds__(256) void k_spmm128(
    const int* __restrict__ rowptr, const uint2* __restrict__ cva,
    const u16* __restrict__ Yb, u16* __restrict__ h2b, int n)
{
    int lane = threadIdx.x & 63;
    int l = lane & 31, half = lane >> 5;
    int row = blockIdx.x * 4 + (threadIdx.x >> 6);
    if (row >= n) return;
    int s = rowptr[row], e = rowptr[row + 1];
    float a0 = 0.f, a1 = 0.f, a2 = 0.f, a3 = 0.f;

    for (int base = s; base < e; base += 64) {
        int p = base + lane;
        int c = 0; float w = 0.f;
        if (p < e) { uint2 cv = cva[p]; c = (int)cv.x; w = __uint_as_float(cv.y); }
        int m = min(64, e - base);
        int j = 0;
        for (; j + 2 <= m; j += 2) {
            int jj = j + half;
            int cj = __shfl(c, jj);
            float wj = __shfl(w, jj);
            uint2 d = *(const uint2*)(Yb + (size_t)cj * 256 + 128 + l * 4);
            a0 += wj * bf2f(d.x & 0xffffu);
            a1 += wj * bf2f(d.x >> 16);
            a2 += wj * bf2f(d.y & 0xffffu);
            a3 += wj * bf2f(d.y >> 16);
        }
        if (j < m) {
            int cj = __shfl(c, j);
            float wj = half ? 0.f : __shfl(w, j);
            uint2 d = *(const uint2*)(Yb + (size_t)cj * 256 + 128 + l * 4);
            a0 += wj * bf2f(d.x & 0xffffu);
            a1 += wj * bf2f(d.x >> 16);
            a2 += wj * bf2f(d.y & 0xffffu);
            a3 += wj * bf2f(d.y >> 16);
        }
    }
    a0 += __shfl_xor(a0, 32);
    a1 += __shfl_xor(a1, 32);
    a2 += __shfl_xor(a2, 32);
    a3 += __shfl_xor(a3, 32);
    if (half == 0) {
        u32 lo = f2bf(a0) | ((u32)f2bf(a1) << 16);
        u32 hi = f2bf(a2) | ((u32)f2bf(a3) << 16);
        *(uint2*)(h2b + (size_t)row * 128 + l * 4) = make_uint2(lo, hi);
    }
}

// ---------------------------------------------------------------------------
// K12: out = relu([gc*h1+(1-gc)*h2, H] @ W_up + b_up) via MFMA bf16.
//      Block: 64 rows x 128 cols, 4 waves (32 cols each). K=256.
// ---------------------------------------------------------------------------
__global__ __launch_bounds__(256) void k_final(
    const u16* __restrict__ Yb, const u16* __restrict__ h2b,
    const float* __restrict__ H, const u16* __restrict__ Wtu,
    const float* __restrict__ bup, const float* __restrict__ gp,
    float* __restrict__ out, int n)
{
    __shared__ __align__(16) u16 Asm[64 * 256];
    int tid = threadIdx.x;
    int r0blk = blockIdx.x * 64;
    float gc = fminf(fmaxf(gp[0], 0.f), 1.f);
    float omg = 1.f - gc;

#pragma unroll
    for (int it = 0; it < 8; ++it) {
        int sidx = tid + it * 256;           // 64 rows x 32 slots
        int row = sidx >> 5, slot = sidx & 31;
        int gi = r0blk + row;
        uint4 w = make_uint4(0u, 0u, 0u, 0u);
        if (gi < n) {
            if (slot < 16) {
                uint4 y = *(const uint4*)(Yb + (size_t)gi * 256 + slot * 8);
                uint4 h2 = *(const uint4*)(h2b + (size_t)gi * 128 + slot * 8);
                u32 yw[4] = {y.x, y.y, y.z, y.w};
                u32 hw[4] = {h2.x, h2.y, h2.z, h2.w};
                u32 ow[4];
#pragma unroll
                for (int q = 0; q < 4; ++q) {
                    float a0 = gc * bf2f(yw[q] & 0xffffu) + omg * bf2f(hw[q] & 0xffffu);
                    float a1 = gc * bf2f(yw[q] >> 16) + omg * bf2f(hw[q] >> 16);
                    ow[q] = f2bf(a0) | ((u32)f2bf(a1) << 16);
                }
                w = make_uint4(ow[0], ow[1], ow[2], ow[3]);
            } else {
                const float4* p = (const float4*)(H + (size_t)gi * 128 + (slot - 16) * 8);
                float4 f0 = p[0], f1 = p[1];
                w.x = f2bf(f0.x) | ((u32)f2bf(f0.y) << 16);
                w.y = f2bf(f0.z) | ((u32)f2bf(f0.w) << 16);
                w.z = f2bf(f1.x) | ((u32)f2bf(f1.y) << 16);
                w.w = f2bf(f1.z) | ((u32)f2bf(f1.w) << 16);
            }
        }
        int grp = slot >> 3, sub = slot & 7;      // swizzle within 8-slot groups
        ((uint4*)Asm)[row * 32 + grp * 8 + (sub ^ (row & 7))] = w;
    }
    __syncthreads();

    int wv = tid >> 6, lane = tid & 63;
    int l15 = lane & 15, lg = lane >> 4;
    f32x4 acc[4][2] = {};
    const u16* Wb = Wtu + (size_t)(wv * 32) * 256;

#pragma unroll
    for (int ks = 0; ks < 8; ++ks) {
        bf16x8 bfr[2];
#pragma unroll
        for (int nt = 0; nt < 2; ++nt)
            bfr[nt] = *(const bf16x8*)(Wb + (size_t)(nt * 16 + l15) * 256 +
                                       ks * 32 + lg * 8);
        bf16x8 afr[4];
#pragma unroll
        for (int mt = 0; mt < 4; ++mt) {
            int row = mt * 16 + l15;
            int slot = ks * 4 + lg;
            int grp = slot >> 3, sub = slot & 7;
            afr[mt] = *(const bf16x8*)(Asm + row * 256 +
                                       (grp * 8 + (sub ^ (row & 7))) * 8);
        }
#pragma unroll
        for (int mt = 0; mt < 4; ++mt)
#pragma unroll
            for (int nt = 0; nt < 2; ++nt)
                acc[mt][nt] = __builtin_amdgcn_mfma_f32_16x16x32_bf16(
                    afr[mt], bfr[nt], acc[mt][nt], 0, 0, 0);
    }

#pragma unroll
    for (int mt = 0; mt < 4; ++mt)
#pragma unroll
        for (int r = 0; r < 4; ++r) {
            int gi = r0blk + mt * 16 + lg * 4 + r;
            if (gi >= n) continue;
#pragma unroll
            for (int nt = 0; nt < 2; ++nt) {
                int col = wv * 32 + nt * 16 + l15;
                float v = acc[mt][nt][r] + bup[col];
                out[(size_t)gi * 128 + col] = fmaxf(v, 0.f);
            }
        }
}

// ---------------------------------------------------------------------------
extern "C" void kernel_launch(void* const* d_in, const int* in_sizes, int n_in,
                              void* d_out, int out_size, void* d_ws,
                              size_t ws_size, hipStream_t stream)
{
    (void)n_in; (void)out_size; (void)ws_size;
    const float* H   = (const float*)d_in[0];
    const int*   ei  = (const int*)d_in[1];
    const float* ea  = (const float*)d_in[2];
    const float* W1  = (const float*)d_in[3];
    const float* W2  = (const float*)d_in[4];
    const float* We1 = (const float*)d_in[5];
    const float* be1 = (const float*)d_in[6];
    const float* We2 = (const float*)d_in[7];
    const float* be2 = (const float*)d_in[8];
    const float* g   = (const float*)d_in[9];
    const float* Wup = (const float*)d_in[10];
    const float* bup = (const float*)d_in[11];

    int n = in_sizes[0] / 128;
    int E = in_sizes[1] / 2;
    const int* src = ei;
    const int* dst = ei + E;
    float* out = (float*)d_out;

    char* wsp = (char*)d_ws;
    auto alloc = [&](size_t bytes) -> char* {
        char* p = wsp;
        wsp += (bytes + 255) & ~(size_t)255;
        return p;
    };
    float* ew     = (float*)alloc((size_t)E * 4);
    int*   tot    = (int*)alloc((size_t)n * 4);
    int*   rowptr = (int*)alloc((size_t)(n + 1) * 4);
    float* dinv   = (float*)alloc((size_t)n * 4);
    uint2* cva    = (uint2*)alloc((size_t)2 * E * 8);
    u16*   Wtc    = (u16*)alloc((size_t)256 * 128 * 2);
    u16*   Wtu    = (u16*)alloc((size_t)128 * 256 * 2);
    u16*   XXb    = (u16*)alloc((size_t)n * 256 * 2);   // hb aliases this
    u16*   Yb     = (u16*)alloc((size_t)n * 256 * 2);
    u16*   h2b    = (u16*)alloc((size_t)n * 128 * 2);
    int*   hb     = (int*)XXb;   // NB*n*4 = 12.8MB <= 25.6MB, dead before k_gemm1

    k_prep<<<256, 256, 0, stream>>>(W1, W2, Wup, Wtc, Wtu);
    k_edge<<<(E + 255) / 256, 256, 0, stream>>>(ea, We1, be1, We2, be2, ew, E);
    k_hist<<<NB, 1024, 0, stream>>>(src, dst, hb, E, n);
    k_rowsum<<<(n + 255) / 256, 256, 0, stream>>>(hb, tot, n);
    k_scan<<<1, 1024, 0, stream>>>(tot, rowptr, n);
    k_off<<<(n + 255) / 256, 256, 0, stream>>>(rowptr, hb, n);
    k_fill<<<NB, 1024, 0, stream>>>(src, dst, ew, hb, cva, E, n);
    k_deg<<<(n + 3) / 4, 256, 0, stream>>>(rowptr, cva, dinv, n);
    k_norm<<<(n + 3) / 4, 256, 0, stream>>>(rowptr, cva, dinv, n);
    k_gemm1<<<(n + 63) / 64, 256, 0, stream>>>(H, Wtc, XXb, n);
    k_spmm256<<<(n + 3) / 4, 256, 0, stream>>>(rowptr, cva, XXb, Yb, n);
    k_spmm128<<<(n + 3) / 4, 256, 0, stream>>>(rowptr, cva, Yb, h2b, n);
    k_final<<<(n + 63) / 64, 256, 0, stream>>>(Yb, h2b, H, Wtu, bup, g, out, n);
}

// Round 4
// 358.439 us; speedup vs baseline: 2.0074x; 1.1659x over previous
//
#include <hip/hip_runtime.h>
#include <stdint.h>

typedef unsigned int u32;
typedef uint16_t u16;
typedef __attribute__((ext_vector_type(8))) short bf16x8;
typedef __attribute__((ext_vector_type(4))) float f32x4;

#define EPSV 1e-12f
#define NB 64            // histogram blocks
#define BINS 12800       // bins per pass (51.2 KB LDS)

__device__ __forceinline__ u16 f2bf(float f) {
    u32 u = __float_as_uint(f);
    return (u16)((u + 0x7fffu + ((u >> 16) & 1u)) >> 16);
}
__device__ __forceinline__ float bf2f(u32 s) { return __uint_as_float(s << 16); }

// ---------------------------------------------------------------------------
// K0: precompute transposed bf16 weights
// ---------------------------------------------------------------------------
__global__ __launch_bounds__(256) void k_prep(
    const float* __restrict__ W1, const float* __restrict__ W2,
    const float* __restrict__ Wup, u16* __restrict__ Wtc,
    u16* __restrict__ Wtu)
{
    int gid = blockIdx.x * 256 + threadIdx.x;
    if (gid < 32768) {
        int c = gid >> 7, k = gid & 127;
        float v = (c < 128) ? W1[k * 128 + c] : W2[k * 128 + (c - 128)];
        Wtc[gid] = f2bf(v);
    } else {
        int g = gid - 32768;      // c*256 + k
        int c = g >> 8, k = g & 255;
        Wtu[g] = f2bf(Wup[k * 128 + c]);
    }
}

// ---------------------------------------------------------------------------
// K1: edge MLP -> sigmoid weights (no atomics)
// ---------------------------------------------------------------------------
__global__ __launch_bounds__(256) void k_edge(
    const float* __restrict__ ea, const float* __restrict__ We1,
    const float* __restrict__ be1, const float* __restrict__ We2,
    const float* __restrict__ be2, float* __restrict__ ew, int E)
{
    __shared__ float w1t[32 * 16];
    __shared__ float b1s[32];
    __shared__ float w2s[32];
    __shared__ float b2s;
    int tid = threadIdx.x;
    for (int i = tid; i < 512; i += 256) {
        int k = i >> 5, j = i & 31;
        w1t[j * 16 + k] = We1[i];
    }
    if (tid < 32) { b1s[tid] = be1[tid]; w2s[tid] = We2[tid]; }
    if (tid == 0) b2s = be2[0];
    __syncthreads();

    int e = blockIdx.x * 256 + tid;
    if (e >= E) return;

    const float4* pa = (const float4*)(ea + (size_t)e * 16);
    float4 A0 = pa[0], A1 = pa[1], A2 = pa[2], A3 = pa[3];
    float av[16] = {A0.x, A0.y, A0.z, A0.w, A1.x, A1.y, A1.z, A1.w,
                    A2.x, A2.y, A2.z, A2.w, A3.x, A3.y, A3.z, A3.w};

    float acc = b2s;
#pragma unroll
    for (int j = 0; j < 32; ++j) {
        const float4* wr = (const float4*)(w1t + j * 16);
        float4 q0 = wr[0], q1 = wr[1], q2 = wr[2], q3 = wr[3];
        float s = b1s[j];
        s += av[0] * q0.x + av[1] * q0.y + av[2] * q0.z + av[3] * q0.w;
        s += av[4] * q1.x + av[5] * q1.y + av[6] * q1.z + av[7] * q1.w;
        s += av[8] * q2.x + av[9] * q2.y + av[10] * q2.z + av[11] * q2.w;
        s += av[12] * q3.x + av[13] * q3.y + av[14] * q3.z + av[15] * q3.w;
        acc += fmaxf(s, 0.f) * w2s[j];
    }
    ew[e] = 1.f / (1.f + __expf(-acc));
}

// ---------------------------------------------------------------------------
// K2: per-block LDS histograms of row ids
// ---------------------------------------------------------------------------
__global__ __launch_bounds__(1024) void k_hist(
    const int* __restrict__ src, const int* __restrict__ dst,
    int* __restrict__ hb, int E, int n)
{
    __shared__ int h[BINS];
    int b = blockIdx.x;
    int E2 = 2 * E;
    int per = (E2 + NB - 1) / NB;
    int lo_e = b * per, hi_e = min(E2, lo_e + per);
    int npass = (n + BINS - 1) / BINS;

    for (int pass = 0; pass < npass; ++pass) {
        int lo = pass * BINS, hi = min(n, lo + BINS);
        for (int i = threadIdx.x; i < BINS; i += 1024) h[i] = 0;
        __syncthreads();
        for (int idx = lo_e + threadIdx.x; idx < hi_e; idx += 1024) {
            int r = (idx < E) ? src[idx] : dst[idx - E];
            if (r >= lo && r < hi) atomicAdd(&h[r - lo], 1);
        }
        __syncthreads();
        for (int i = threadIdx.x; i < hi - lo; i += 1024)
            hb[(size_t)b * n + lo + i] = h[i];
        __syncthreads();
    }
}

// ---------------------------------------------------------------------------
// K3: tot[r] = sum_b hb[b][r]
// ---------------------------------------------------------------------------
__global__ __launch_bounds__(256) void k_rowsum(
    const int* __restrict__ hb, int* __restrict__ tot, int n)
{
    int r = blockIdx.x * 256 + threadIdx.x;
    if (r >= n) return;
    int s = 0;
#pragma unroll 8
    for (int b = 0; b < NB; ++b) s += hb[(size_t)b * n + r];
    tot[r] = s;
}

// ---------------------------------------------------------------------------
// K4: single-block exclusive scan: tot -> rowptr
// ---------------------------------------------------------------------------
__global__ __launch_bounds__(1024) void k_scan(
    const int* __restrict__ tot, int* __restrict__ rowptr, int n)
{
    int tid = threadIdx.x, lane = tid & 63, w = tid >> 6;
    __shared__ int wsum[16];
    int running = 0;
    for (int base = 0; base < n; base += 1024) {
        int x = (base + tid < n) ? tot[base + tid] : 0;
        int v = x;
#pragma unroll
        for (int d = 1; d < 64; d <<= 1) {
            int t = __shfl_up(v, d);
            if (lane >= d) v += t;
        }
        if (lane == 63) wsum[w] = v;
        __syncthreads();
        if (w == 0) {
            int s = (lane < 16) ? wsum[lane] : 0;
#pragma unroll
            for (int d = 1; d < 16; d <<= 1) {
                int t = __shfl_up(s, d);
                if (lane >= d) s += t;
            }
            if (lane < 16) wsum[lane] = s;
        }
        __syncthreads();
        int waveoff = (w == 0) ? 0 : wsum[w - 1];
        if (base + tid < n) rowptr[base + tid] = running + waveoff + v - x;
        running += wsum[15];
        __syncthreads();
    }
    if (tid == 0) rowptr[n] = running;
}

// ---------------------------------------------------------------------------
// K5: hb[b][r] <- rowptr[r] + prefix_{b'<b} hb[b'][r]
// ---------------------------------------------------------------------------
__global__ __launch_bounds__(256) void k_off(
    const int* __restrict__ rowptr, int* __restrict__ hb, int n)
{
    int r = blockIdx.x * 256 + threadIdx.x;
    if (r >= n) return;
    int run = rowptr[r];
    for (int b = 0; b < NB; ++b) {
        int t = hb[(size_t)b * n + r];
        hb[(size_t)b * n + r] = run;
        run += t;
    }
}

// ---------------------------------------------------------------------------
// K6: fill CSR. Positions via LDS atomicAdd on preloaded per-block offsets.
// ---------------------------------------------------------------------------
__global__ __launch_bounds__(1024) void k_fill(
    const int* __restrict__ src, const int* __restrict__ dst,
    const float* __restrict__ ew, int* __restrict__ hb,
    uint2* __restrict__ cva, int E, int n)
{
    __shared__ int hofs[BINS];
    int b = blockIdx.x;
    int E2 = 2 * E;
    int per = (E2 + NB - 1) / NB;
    int lo_e = b * per, hi_e = min(E2, lo_e + per);
    int npass = (n + BINS - 1) / BINS;

    for (int pass = 0; pass < npass; ++pass) {
        int lo = pass * BINS, hi = min(n, lo + BINS);
        for (int i = threadIdx.x; i < hi - lo; i += 1024)
            hofs[i] = hb[(size_t)b * n + lo + i];
        __syncthreads();
        for (int idx = lo_e + threadIdx.x; idx < hi_e; idx += 1024) {
            int e = (idx < E) ? idx : idx - E;
            int r, c;
            if (idx < E) { r = src[e]; c = dst[e]; }
            else         { r = dst[e]; c = src[e]; }
            if (r >= lo && r < hi) {
                int pos = atomicAdd(&hofs[r - lo], 1);
                cva[pos] = make_uint2((u32)c, __float_as_uint(ew[e]));
            }
        }
        __syncthreads();
    }
}

// ---------------------------------------------------------------------------
// K7: deg -> dinv (wave per row)
// ---------------------------------------------------------------------------
__global__ __launch_bounds__(256) void k_deg(
    const int* __restrict__ rowptr, const uint2* __restrict__ cva,
    float* __restrict__ dinv, int n)
{
    int lane = threadIdx.x & 63;
    int row = blockIdx.x * 4 + (threadIdx.x >> 6);
    if (row >= n) return;
    int s = rowptr[row], e = rowptr[row + 1];
    float sum = 0.f;
    for (int p = s + lane; p < e; p += 64) sum += __uint_as_float(cva[p].y);
#pragma unroll
    for (int d = 1; d < 64; d <<= 1) sum += __shfl_xor(sum, d);
    if (lane == 0) dinv[row] = rsqrtf(sum + EPSV);
}

// ---------------------------------------------------------------------------
// K8: normalize vals in place: v *= dinv[r]*dinv[c]
// ---------------------------------------------------------------------------
__global__ __launch_bounds__(256) void k_norm(
    const int* __restrict__ rowptr, uint2* __restrict__ cva,
    const float* __restrict__ dinv, int n)
{
    int lane = threadIdx.x & 63;
    int row = blockIdx.x * 4 + (threadIdx.x >> 6);
    if (row >= n) return;
    int s = rowptr[row], e = rowptr[row + 1];
    float dr = dinv[row];
    for (int p = s + lane; p < e; p += 64) {
        uint2 cv = cva[p];
        float v = __uint_as_float(cv.y) * dr * dinv[cv.x];
        cva[p] = make_uint2(cv.x, __float_as_uint(v));
    }
}

// ---------------------------------------------------------------------------
// K9: XX = H @ [W1|W2] via MFMA bf16. Block: 64 rows x 256 cols, 4 waves.
// ---------------------------------------------------------------------------
__global__ __launch_bounds__(256) void k_gemm1(
    const float* __restrict__ H, const u16* __restrict__ Wtc,
    u16* __restrict__ XXb, int n)
{
    __shared__ __align__(16) u16 Asm[64 * 128];
    int tid = threadIdx.x;
    int r0blk = blockIdx.x * 64;

#pragma unroll
    for (int it = 0; it < 4; ++it) {
        int sidx = tid + it * 256;           // 64 rows x 16 slots
        int row = sidx >> 4, slot = sidx & 15;
        int gi = r0blk + row;
        float4 f0 = make_float4(0.f, 0.f, 0.f, 0.f), f1 = f0;
        if (gi < n) {
            const float4* p = (const float4*)(H + (size_t)gi * 128 + slot * 8);
            f0 = p[0]; f1 = p[1];
        }
        uint4 w;
        w.x = f2bf(f0.x) | ((u32)f2bf(f0.y) << 16);
        w.y = f2bf(f0.z) | ((u32)f2bf(f0.w) << 16);
        w.z = f2bf(f1.x) | ((u32)f2bf(f1.y) << 16);
        w.w = f2bf(f1.z) | ((u32)f2bf(f1.w) << 16);
        ((uint4*)Asm)[row * 16 + (slot ^ (row & 7))] = w;
    }
    __syncthreads();

    int wv = tid >> 6, lane = tid & 63;
    int l15 = lane & 15, lg = lane >> 4;
    f32x4 acc[4][4] = {};
    const u16* Wb = Wtc + (size_t)(wv * 64) * 128;

#pragma unroll
    for (int ks = 0; ks < 4; ++ks) {
        bf16x8 bfr[4];
#pragma unroll
        for (int nt = 0; nt < 4; ++nt)
            bfr[nt] = *(const bf16x8*)(Wb + (size_t)(nt * 16 + l15) * 128 +
                                       ks * 32 + lg * 8);
        bf16x8 afr[4];
#pragma unroll
        for (int mt = 0; mt < 4; ++mt) {
            int row = mt * 16 + l15;
            int slot = ks * 4 + lg;
            afr[mt] = *(const bf16x8*)(Asm + row * 128 + (slot ^ (row & 7)) * 8);
        }
#pragma unroll
        for (int mt = 0; mt < 4; ++mt)
#pragma unroll
            for (int nt = 0; nt < 4; ++nt)
                acc[mt][nt] = __builtin_amdgcn_mfma_f32_16x16x32_bf16(
                    afr[mt], bfr[nt], acc[mt][nt], 0, 0, 0);
    }

#pragma unroll
    for (int mt = 0; mt < 4; ++mt)
#pragma unroll
        for (int r = 0; r < 4; ++r) {
            int gi = r0blk + mt * 16 + lg * 4 + r;
            if (gi >= n) continue;
#pragma unroll
            for (int nt = 0; nt < 4; ++nt)
                XXb[(size_t)gi * 256 + wv * 64 + nt * 16 + l15] =
                    f2bf(acc[mt][nt][r]);
        }
}

// ---------------------------------------------------------------------------
// K10: generic 128-col SpMM, quarter-wave gather (16 lanes x 16B = one row).
//   MIX: out = gc * Xm[row][0:128] + (1-gc) * (A @ Xg)[row]
//  !MIX: out = (A @ Xg)[row]
// ---------------------------------------------------------------------------
template <bool MIX>
__global__ __launch_bounds__(256) void k_spmm(
    const int* __restrict__ rowptr, const uint2* __restrict__ cva,
    const u16* __restrict__ Xg, int gstride, int goff,
    const u16* __restrict__ Xm, u16* __restrict__ outb,
    const float* __restrict__ gp, int n)
{
    int lane = threadIdx.x & 63;
    int q = lane >> 4, l16 = lane & 15;
    int row = blockIdx.x * 4 + (threadIdx.x >> 6);
    if (row >= n) return;
    int s = rowptr[row], e = rowptr[row + 1];
    float a[8] = {0.f, 0.f, 0.f, 0.f, 0.f, 0.f, 0.f, 0.f};

    for (int base = s; base < e; base += 64) {
        int p = base + lane;
        int c = 0; float w = 0.f;
        if (p < e) { uint2 cv = cva[p]; c = (int)cv.x; w = __uint_as_float(cv.y); }
        int m = min(64, e - base);
#pragma unroll 2
        for (int j = 0; j < m; j += 4) {
            int jj = j + q;                       // <= 63 always
            int cj = __shfl(c, jj);
            float wj = __shfl(w, jj);             // 0 beyond row end
            uint4 d = *(const uint4*)(Xg + (size_t)cj * gstride + goff + l16 * 8);
            a[0] += wj * bf2f(d.x & 0xffffu);
            a[1] += wj * bf2f(d.x >> 16);
            a[2] += wj * bf2f(d.y & 0xffffu);
            a[3] += wj * bf2f(d.y >> 16);
            a[4] += wj * bf2f(d.z & 0xffffu);
            a[5] += wj * bf2f(d.z >> 16);
            a[6] += wj * bf2f(d.w & 0xffffu);
            a[7] += wj * bf2f(d.w >> 16);
        }
    }
#pragma unroll
    for (int k = 0; k < 8; ++k) {
        a[k] += __shfl_xor(a[k], 16);
        a[k] += __shfl_xor(a[k], 32);
    }
    if (q == 0) {
        if (MIX) {
            float gc = fminf(fmaxf(gp[0], 0.f), 1.f);
            float omg = 1.f - gc;
            uint4 x1 = *(const uint4*)(Xm + (size_t)row * 256 + l16 * 8);
            a[0] = gc * bf2f(x1.x & 0xffffu) + omg * a[0];
            a[1] = gc * bf2f(x1.x >> 16)     + omg * a[1];
            a[2] = gc * bf2f(x1.y & 0xffffu) + omg * a[2];
            a[3] = gc * bf2f(x1.y >> 16)     + omg * a[3];
            a[4] = gc * bf2f(x1.z & 0xffffu) + omg * a[4];
            a[5] = gc * bf2f(x1.z >> 16)     + omg * a[5];
            a[6] = gc * bf2f(x1.w & 0xffffu) + omg * a[6];
            a[7] = gc * bf2f(x1.w >> 16)     + omg * a[7];
        }
        uint4 o;
        o.x = f2bf(a[0]) | ((u32)f2bf(a[1]) << 16);
        o.y = f2bf(a[2]) | ((u32)f2bf(a[3]) << 16);
        o.z = f2bf(a[4]) | ((u32)f2bf(a[5]) << 16);
        o.w = f2bf(a[6]) | ((u32)f2bf(a[7]) << 16);
        *(uint4*)(outb + (size_t)row * 128 + l16 * 8) = o;
    }
}

// ---------------------------------------------------------------------------
// K12: out = relu([agg, H] @ W_up + b_up) via MFMA bf16.
// ---------------------------------------------------------------------------
__global__ __launch_bounds__(256) void k_final(
    const u16* __restrict__ aggb, const float* __restrict__ H,
    const u16* __restrict__ Wtu, const float* __restrict__ bup,
    float* __restrict__ out, int n)
{
    __shared__ __align__(16) u16 Asm[64 * 256];
    int tid = threadIdx.x;
    int r0blk = blockIdx.x * 64;

#pragma unroll
    for (int it = 0; it < 8; ++it) {
        int sidx = tid + it * 256;           // 64 rows x 32 slots
        int row = sidx >> 5, slot = sidx & 31;
        int gi = r0blk + row;
        uint4 w = make_uint4(0u, 0u, 0u, 0u);
        if (gi < n) {
            if (slot < 16) {
                w = *(const uint4*)(aggb + (size_t)gi * 128 + slot * 8);
            } else {
                const float4* p = (const float4*)(H + (size_t)gi * 128 + (slot - 16) * 8);
                float4 f0 = p[0], f1 = p[1];
                w.x = f2bf(f0.x) | ((u32)f2bf(f0.y) << 16);
                w.y = f2bf(f0.z) | ((u32)f2bf(f0.w) << 16);
                w.z = f2bf(f1.x) | ((u32)f2bf(f1.y) << 16);
                w.w = f2bf(f1.z) | ((u32)f2bf(f1.w) << 16);
            }
        }
        int grp = slot >> 3, sub = slot & 7;
        ((uint4*)Asm)[row * 32 + grp * 8 + (sub ^ (row & 7))] = w;
    }
    __syncthreads();

    int wv = tid >> 6, lane = tid & 63;
    int l15 = lane & 15, lg = lane >> 4;
    f32x4 acc[4][2] = {};
    const u16* Wb = Wtu + (size_t)(wv * 32) * 256;

#pragma unroll
    for (int ks = 0; ks < 8; ++ks) {
        bf16x8 bfr[2];
#pragma unroll
        for (int nt = 0; nt < 2; ++nt)
            bfr[nt] = *(const bf16x8*)(Wb + (size_t)(nt * 16 + l15) * 256 +
                                       ks * 32 + lg * 8);
        bf16x8 afr[4];
#pragma unroll
        for (int mt = 0; mt < 4; ++mt) {
            int row = mt * 16 + l15;
            int slot = ks * 4 + lg;
            int grp = slot >> 3, sub = slot & 7;
            afr[mt] = *(const bf16x8*)(Asm + row * 256 +
                                       (grp * 8 + (sub ^ (row & 7))) * 8);
        }
#pragma unroll
        for (int mt = 0; mt < 4; ++mt)
#pragma unroll
            for (int nt = 0; nt < 2; ++nt)
                acc[mt][nt] = __builtin_amdgcn_mfma_f32_16x16x32_bf16(
                    afr[mt], bfr[nt], acc[mt][nt], 0, 0, 0);
    }

#pragma unroll
    for (int mt = 0; mt < 4; ++mt)
#pragma unroll
        for (int r = 0; r < 4; ++r) {
            int gi = r0blk + mt * 16 + lg * 4 + r;
            if (gi >= n) continue;
#pragma unroll
            for (int nt = 0; nt < 2; ++nt) {
                int col = wv * 32 + nt * 16 + l15;
                float v = acc[mt][nt][r] + bup[col];
                out[(size_t)gi * 128 + col] = fmaxf(v, 0.f);
            }
        }
}

// ---------------------------------------------------------------------------
extern "C" void kernel_launch(void* const* d_in, const int* in_sizes, int n_in,
                              void* d_out, int out_size, void* d_ws,
                              size_t ws_size, hipStream_t stream)
{
    (void)n_in; (void)out_size; (void)ws_size;
    const float* H   = (const float*)d_in[0];
    const int*   ei  = (const int*)d_in[1];
    const float* ea  = (const float*)d_in[2];
    const float* W1  = (const float*)d_in[3];
    const float* W2  = (const float*)d_in[4];
    const float* We1 = (const float*)d_in[5];
    const float* be1 = (const float*)d_in[6];
    const float* We2 = (const float*)d_in[7];
    const float* be2 = (const float*)d_in[8];
    const float* g   = (const float*)d_in[9];
    const float* Wup = (const float*)d_in[10];
    const float* bup = (const float*)d_in[11];

    int n = in_sizes[0] / 128;
    int E = in_sizes[1] / 2;
    const int* src = ei;
    const int* dst = ei + E;
    float* out = (float*)d_out;

    char* wsp = (char*)d_ws;
    auto alloc = [&](size_t bytes) -> char* {
        char* p = wsp;
        wsp += (bytes + 255) & ~(size_t)255;
        return p;
    };
    float* ew     = (float*)alloc((size_t)E * 4);
    int*   tot    = (int*)alloc((size_t)n * 4);
    int*   rowptr = (int*)alloc((size_t)(n + 1) * 4);
    float* dinv   = (float*)alloc((size_t)n * 4);
    uint2* cva    = (uint2*)alloc((size_t)2 * E * 8);
    u16*   Wtc    = (u16*)alloc((size_t)256 * 128 * 2);
    u16*   Wtu    = (u16*)alloc((size_t)128 * 256 * 2);
    u16*   XXb    = (u16*)alloc((size_t)n * 256 * 2);   // hb aliases this
    u16*   Zb     = (u16*)alloc((size_t)n * 128 * 2);
    u16*   aggb   = (u16*)alloc((size_t)n * 128 * 2);
    int*   hb     = (int*)XXb;   // NB*n*4 = 12.8MB <= 25.6MB, dead before k_gemm1

    k_prep<<<256, 256, 0, stream>>>(W1, W2, Wup, Wtc, Wtu);
    k_edge<<<(E + 255) / 256, 256, 0, stream>>>(ea, We1, be1, We2, be2, ew, E);
    k_hist<<<NB, 1024, 0, stream>>>(src, dst, hb, E, n);
    k_rowsum<<<(n + 255) / 256, 256, 0, stream>>>(hb, tot, n);
    k_scan<<<1, 1024, 0, stream>>>(tot, rowptr, n);
    k_off<<<(n + 255) / 256, 256, 0, stream>>>(rowptr, hb, n);
    k_fill<<<NB, 1024, 0, stream>>>(src, dst, ew, hb, cva, E, n);
    k_deg<<<(n + 3) / 4, 256, 0, stream>>>(rowptr, cva, dinv, n);
    k_norm<<<(n + 3) / 4, 256, 0, stream>>>(rowptr, cva, dinv, n);
    k_gemm1<<<(n + 63) / 64, 256, 0, stream>>>(H, Wtc, XXb, n);
    // t = A @ X2 ; Z = gc*X1 + (1-gc)*t
    k_spmm<true><<<(n + 3) / 4, 256, 0, stream>>>(rowptr, cva, XXb, 256, 128,
                                                  XXb, Zb, g, n);
    // agg = A @ Z
    k_spmm<false><<<(n + 3) / 4, 256, 0, stream>>>(rowptr, cva, Zb, 128, 0,
                                                   nullptr, aggb, g, n);
    k_final<<<(n + 63) / 64, 256, 0, stream>>>(aggb, H, Wtu, bup, out, n);
}

// Round 5
// 339.047 us; speedup vs baseline: 2.1222x; 1.0572x over previous
//
#include <hip/hip_runtime.h>
#include <stdint.h>

typedef unsigned int u32;
typedef uint16_t u16;
typedef __attribute__((ext_vector_type(8))) short bf16x8;
typedef __attribute__((ext_vector_type(4))) float f32x4;

#define EPSV 1e-12f
#define NB 256           // histogram blocks (1 per CU)
#define BINS_H 25600     // hist bins/pass (u16 packed, 51.2 KB LDS, 2 passes)
#define BINS_F 12800     // fill bins/pass (int, 51.2 KB LDS, 4 passes)

__device__ __forceinline__ u16 f2bf(float f) {
    u32 u = __float_as_uint(f);
    return (u16)((u + 0x7fffu + ((u >> 16) & 1u)) >> 16);
}
__device__ __forceinline__ float bf2f(u32 s) { return __uint_as_float(s << 16); }

// ---------------------------------------------------------------------------
// K0: precompute transposed bf16 weights
// ---------------------------------------------------------------------------
__global__ __launch_bounds__(256) void k_prep(
    const float* __restrict__ W1, const float* __restrict__ W2,
    const float* __restrict__ Wup, u16* __restrict__ Wtc,
    u16* __restrict__ Wtu)
{
    int gid = blockIdx.x * 256 + threadIdx.x;
    if (gid < 32768) {
        int c = gid >> 7, k = gid & 127;
        float v = (c < 128) ? W1[k * 128 + c] : W2[k * 128 + (c - 128)];
        Wtc[gid] = f2bf(v);
    } else {
        int g = gid - 32768;      // c*256 + k
        int c = g >> 8, k = g & 255;
        Wtu[g] = f2bf(Wup[k * 128 + c]);
    }
}

// ---------------------------------------------------------------------------
// K1: edge MLP -> sigmoid weights (no atomics)
// ---------------------------------------------------------------------------
__global__ __launch_bounds__(256) void k_edge(
    const float* __restrict__ ea, const float* __restrict__ We1,
    const float* __restrict__ be1, const float* __restrict__ We2,
    const float* __restrict__ be2, float* __restrict__ ew, int E)
{
    __shared__ float w1t[32 * 16];
    __shared__ float b1s[32];
    __shared__ float w2s[32];
    __shared__ float b2s;
    int tid = threadIdx.x;
    for (int i = tid; i < 512; i += 256) {
        int k = i >> 5, j = i & 31;
        w1t[j * 16 + k] = We1[i];
    }
    if (tid < 32) { b1s[tid] = be1[tid]; w2s[tid] = We2[tid]; }
    if (tid == 0) b2s = be2[0];
    __syncthreads();

    int e = blockIdx.x * 256 + tid;
    if (e >= E) return;

    const float4* pa = (const float4*)(ea + (size_t)e * 16);
    float4 A0 = pa[0], A1 = pa[1], A2 = pa[2], A3 = pa[3];
    float av[16] = {A0.x, A0.y, A0.z, A0.w, A1.x, A1.y, A1.z, A1.w,
                    A2.x, A2.y, A2.z, A2.w, A3.x, A3.y, A3.z, A3.w};

    float acc = b2s;
#pragma unroll
    for (int j = 0; j < 32; ++j) {
        const float4* wr = (const float4*)(w1t + j * 16);
        float4 q0 = wr[0], q1 = wr[1], q2 = wr[2], q3 = wr[3];
        float s = b1s[j];
        s += av[0] * q0.x + av[1] * q0.y + av[2] * q0.z + av[3] * q0.w;
        s += av[4] * q1.x + av[5] * q1.y + av[6] * q1.z + av[7] * q1.w;
        s += av[8] * q2.x + av[9] * q2.y + av[10] * q2.z + av[11] * q2.w;
        s += av[12] * q3.x + av[13] * q3.y + av[14] * q3.z + av[15] * q3.w;
        acc += fmaxf(s, 0.f) * w2s[j];
    }
    ew[e] = 1.f / (1.f + __expf(-acc));
}

// ---------------------------------------------------------------------------
// K2: per-block LDS histograms of row ids (u16 bins packed 2-per-u32)
// ---------------------------------------------------------------------------
__global__ __launch_bounds__(1024) void k_hist(
    const int* __restrict__ src, const int* __restrict__ dst,
    int* __restrict__ hb, int E, int n)
{
    __shared__ u32 h[BINS_H / 2];
    int b = blockIdx.x;
    int E2 = 2 * E;
    int per = (E2 + NB - 1) / NB;
    int lo_e = b * per, hi_e = min(E2, lo_e + per);
    int npass = (n + BINS_H - 1) / BINS_H;

    for (int pass = 0; pass < npass; ++pass) {
        int lo = pass * BINS_H, hi = min(n, lo + BINS_H);
        for (int i = threadIdx.x; i < BINS_H / 2; i += 1024) h[i] = 0;
        __syncthreads();
        for (int idx = lo_e + threadIdx.x; idx < hi_e; idx += 1024) {
            int r = (idx < E) ? src[idx] : dst[idx - E];
            if (r >= lo && r < hi) {
                int rr = r - lo;
                atomicAdd(&h[rr >> 1], 1u << ((rr & 1) * 16));
            }
        }
        __syncthreads();
        for (int i = threadIdx.x; i < hi - lo; i += 1024)
            hb[(size_t)b * n + lo + i] = (h[i >> 1] >> ((i & 1) * 16)) & 0xffffu;
        __syncthreads();
    }
}

// ---------------------------------------------------------------------------
// K3: tot[r] = sum_b hb[b][r]
// ---------------------------------------------------------------------------
__global__ __launch_bounds__(256) void k_rowsum(
    const int* __restrict__ hb, int* __restrict__ tot, int n)
{
    int r = blockIdx.x * 256 + threadIdx.x;
    if (r >= n) return;
    int s = 0;
#pragma unroll 8
    for (int b = 0; b < NB; ++b) s += hb[(size_t)b * n + r];
    tot[r] = s;
}

// ---------------------------------------------------------------------------
// K4: single-block exclusive scan: tot -> rowptr
// ---------------------------------------------------------------------------
__global__ __launch_bounds__(1024) void k_scan(
    const int* __restrict__ tot, int* __restrict__ rowptr, int n)
{
    int tid = threadIdx.x, lane = tid & 63, w = tid >> 6;
    __shared__ int wsum[16];
    int running = 0;
    for (int base = 0; base < n; base += 1024) {
        int x = (base + tid < n) ? tot[base + tid] : 0;
        int v = x;
#pragma unroll
        for (int d = 1; d < 64; d <<= 1) {
            int t = __shfl_up(v, d);
            if (lane >= d) v += t;
        }
        if (lane == 63) wsum[w] = v;
        __syncthreads();
        if (w == 0) {
            int s = (lane < 16) ? wsum[lane] : 0;
#pragma unroll
            for (int d = 1; d < 16; d <<= 1) {
                int t = __shfl_up(s, d);
                if (lane >= d) s += t;
            }
            if (lane < 16) wsum[lane] = s;
        }
        __syncthreads();
        int waveoff = (w == 0) ? 0 : wsum[w - 1];
        if (base + tid < n) rowptr[base + tid] = running + waveoff + v - x;
        running += wsum[15];
        __syncthreads();
    }
    if (tid == 0) rowptr[n] = running;
}

// ---------------------------------------------------------------------------
// K5: hb[b][r] <- rowptr[r] + prefix_{b'<b} hb[b'][r]
// ---------------------------------------------------------------------------
__global__ __launch_bounds__(256) void k_off(
    const int* __restrict__ rowptr, int* __restrict__ hb, int n)
{
    int r = blockIdx.x * 256 + threadIdx.x;
    if (r >= n) return;
    int run = rowptr[r];
    for (int b = 0; b < NB; ++b) {
        int t = hb[(size_t)b * n + r];
        hb[(size_t)b * n + r] = run;
        run += t;
    }
}

// ---------------------------------------------------------------------------
// K6: fill CSR. Positions via LDS atomicAdd on preloaded per-block offsets.
// ---------------------------------------------------------------------------
__global__ __launch_bounds__(1024) void k_fill(
    const int* __restrict__ src, const int* __restrict__ dst,
    const float* __restrict__ ew, int* __restrict__ hb,
    uint2* __restrict__ cva, int E, int n)
{
    __shared__ int hofs[BINS_F];
    int b = blockIdx.x;
    int E2 = 2 * E;
    int per = (E2 + NB - 1) / NB;
    int lo_e = b * per, hi_e = min(E2, lo_e + per);
    int npass = (n + BINS_F - 1) / BINS_F;

    for (int pass = 0; pass < npass; ++pass) {
        int lo = pass * BINS_F, hi = min(n, lo + BINS_F);
        for (int i = threadIdx.x; i < hi - lo; i += 1024)
            hofs[i] = hb[(size_t)b * n + lo + i];
        __syncthreads();
        for (int idx = lo_e + threadIdx.x; idx < hi_e; idx += 1024) {
            int e = (idx < E) ? idx : idx - E;
            int r, c;
            if (idx < E) { r = src[e]; c = dst[e]; }
            else         { r = dst[e]; c = src[e]; }
            if (r >= lo && r < hi) {
                int pos = atomicAdd(&hofs[r - lo], 1);
                cva[pos] = make_uint2((u32)c, __float_as_uint(ew[e]));
            }
        }
        __syncthreads();
    }
}

// ---------------------------------------------------------------------------
// K7: deg -> dinv (wave per row)
// ---------------------------------------------------------------------------
__global__ __launch_bounds__(256) void k_deg(
    const int* __restrict__ rowptr, const uint2* __restrict__ cva,
    float* __restrict__ dinv, int n)
{
    int lane = threadIdx.x & 63;
    int row = blockIdx.x * 4 + (threadIdx.x >> 6);
    if (row >= n) return;
    int s = rowptr[row], e = rowptr[row + 1];
    float sum = 0.f;
    for (int p = s + lane; p < e; p += 64) sum += __uint_as_float(cva[p].y);
#pragma unroll
    for (int d = 1; d < 64; d <<= 1) sum += __shfl_xor(sum, d);
    if (lane == 0) dinv[row] = rsqrtf(sum + EPSV);
}

// ---------------------------------------------------------------------------
// K8: normalize vals in place: v *= dinv[r]*dinv[c]
// ---------------------------------------------------------------------------
__global__ __launch_bounds__(256) void k_norm(
    const int* __restrict__ rowptr, uint2* __restrict__ cva,
    const float* __restrict__ dinv, int n)
{
    int lane = threadIdx.x & 63;
    int row = blockIdx.x * 4 + (threadIdx.x >> 6);
    if (row >= n) return;
    int s = rowptr[row], e = rowptr[row + 1];
    float dr = dinv[row];
    for (int p = s + lane; p < e; p += 64) {
        uint2 cv = cva[p];
        float v = __uint_as_float(cv.y) * dr * dinv[cv.x];
        cva[p] = make_uint2(cv.x, __float_as_uint(v));
    }
}

// ---------------------------------------------------------------------------
// K9: XX = H @ [W1|W2] via MFMA bf16. Block: 64 rows x 256 cols, 4 waves.
// ---------------------------------------------------------------------------
__global__ __launch_bounds__(256) void k_gemm1(
    const float* __restrict__ H, const u16* __restrict__ Wtc,
    u16* __restrict__ XXb, int n)
{
    __shared__ __align__(16) u16 Asm[64 * 128];
    int tid = threadIdx.x;
    int r0blk = blockIdx.x * 64;

#pragma unroll
    for (int it = 0; it < 4; ++it) {
        int sidx = tid + it * 256;           // 64 rows x 16 slots
        int row = sidx >> 4, slot = sidx & 15;
        int gi = r0blk + row;
        float4 f0 = make_float4(0.f, 0.f, 0.f, 0.f), f1 = f0;
        if (gi < n) {
            const float4* p = (const float4*)(H + (size_t)gi * 128 + slot * 8);
            f0 = p[0]; f1 = p[1];
        }
        uint4 w;
        w.x = f2bf(f0.x) | ((u32)f2bf(f0.y) << 16);
        w.y = f2bf(f0.z) | ((u32)f2bf(f0.w) << 16);
        w.z = f2bf(f1.x) | ((u32)f2bf(f1.y) << 16);
        w.w = f2bf(f1.z) | ((u32)f2bf(f1.w) << 16);
        ((uint4*)Asm)[row * 16 + (slot ^ (row & 7))] = w;
    }
    __syncthreads();

    int wv = tid >> 6, lane = tid & 63;
    int l15 = lane & 15, lg = lane >> 4;
    f32x4 acc[4][4] = {};
    const u16* Wb = Wtc + (size_t)(wv * 64) * 128;

#pragma unroll
    for (int ks = 0; ks < 4; ++ks) {
        bf16x8 bfr[4];
#pragma unroll
        for (int nt = 0; nt < 4; ++nt)
            bfr[nt] = *(const bf16x8*)(Wb + (size_t)(nt * 16 + l15) * 128 +
                                       ks * 32 + lg * 8);
        bf16x8 afr[4];
#pragma unroll
        for (int mt = 0; mt < 4; ++mt) {
            int row = mt * 16 + l15;
            int slot = ks * 4 + lg;
            afr[mt] = *(const bf16x8*)(Asm + row * 128 + (slot ^ (row & 7)) * 8);
        }
#pragma unroll
        for (int mt = 0; mt < 4; ++mt)
#pragma unroll
            for (int nt = 0; nt < 4; ++nt)
                acc[mt][nt] = __builtin_amdgcn_mfma_f32_16x16x32_bf16(
                    afr[mt], bfr[nt], acc[mt][nt], 0, 0, 0);
    }

#pragma unroll
    for (int mt = 0; mt < 4; ++mt)
#pragma unroll
        for (int r = 0; r < 4; ++r) {
            int gi = r0blk + mt * 16 + lg * 4 + r;
            if (gi >= n) continue;
#pragma unroll
            for (int nt = 0; nt < 4; ++nt)
                XXb[(size_t)gi * 256 + wv * 64 + nt * 16 + l15] =
                    f2bf(acc[mt][nt][r]);
        }
}

// ---------------------------------------------------------------------------
// K10: generic 128-col SpMM, quarter-wave gather (16 lanes x 16B = one row).
//   MIX: out = gc * Xm[row][0:128] + (1-gc) * (A @ Xg)[row]
//  !MIX: out = (A @ Xg)[row]
// ---------------------------------------------------------------------------
template <bool MIX>
__global__ __launch_bounds__(256) void k_spmm(
    const int* __restrict__ rowptr, const uint2* __restrict__ cva,
    const u16* __restrict__ Xg, int gstride, int goff,
    const u16* __restrict__ Xm, u16* __restrict__ outb,
    const float* __restrict__ gp, int n)
{
    int lane = threadIdx.x & 63;
    int q = lane >> 4, l16 = lane & 15;
    int row = blockIdx.x * 4 + (threadIdx.x >> 6);
    if (row >= n) return;
    int s = rowptr[row], e = rowptr[row + 1];
    float a[8] = {0.f, 0.f, 0.f, 0.f, 0.f, 0.f, 0.f, 0.f};

    for (int base = s; base < e; base += 64) {
        int p = base + lane;
        int c = 0; float w = 0.f;
        if (p < e) { uint2 cv = cva[p]; c = (int)cv.x; w = __uint_as_float(cv.y); }
        int m = min(64, e - base);
#pragma unroll 2
        for (int j = 0; j < m; j += 4) {
            int jj = j + q;                       // <= 63 always
            int cj = __shfl(c, jj);
            float wj = __shfl(w, jj);             // 0 beyond row end
            uint4 d = *(const uint4*)(Xg + (size_t)cj * gstride + goff + l16 * 8);
            a[0] += wj * bf2f(d.x & 0xffffu);
            a[1] += wj * bf2f(d.x >> 16);
            a[2] += wj * bf2f(d.y & 0xffffu);
            a[3] += wj * bf2f(d.y >> 16);
            a[4] += wj * bf2f(d.z & 0xffffu);
            a[5] += wj * bf2f(d.z >> 16);
            a[6] += wj * bf2f(d.w & 0xffffu);
            a[7] += wj * bf2f(d.w >> 16);
        }
    }
#pragma unroll
    for (int k = 0; k < 8; ++k) {
        a[k] += __shfl_xor(a[k], 16);
        a[k] += __shfl_xor(a[k], 32);
    }
    if (q == 0) {
        if (MIX) {
            float gc = fminf(fmaxf(gp[0], 0.f), 1.f);
            float omg = 1.f - gc;
            uint4 x1 = *(const uint4*)(Xm + (size_t)row * 256 + l16 * 8);
            a[0] = gc * bf2f(x1.x & 0xffffu) + omg * a[0];
            a[1] = gc * bf2f(x1.x >> 16)     + omg * a[1];
            a[2] = gc * bf2f(x1.y & 0xffffu) + omg * a[2];
            a[3] = gc * bf2f(x1.y >> 16)     + omg * a[3];
            a[4] = gc * bf2f(x1.z & 0xffffu) + omg * a[4];
            a[5] = gc * bf2f(x1.z >> 16)     + omg * a[5];
            a[6] = gc * bf2f(x1.w & 0xffffu) + omg * a[6];
            a[7] = gc * bf2f(x1.w >> 16)     + omg * a[7];
        }
        uint4 o;
        o.x = f2bf(a[0]) | ((u32)f2bf(a[1]) << 16);
        o.y = f2bf(a[2]) | ((u32)f2bf(a[3]) << 16);
        o.z = f2bf(a[4]) | ((u32)f2bf(a[5]) << 16);
        o.w = f2bf(a[6]) | ((u32)f2bf(a[7]) << 16);
        *(uint4*)(outb + (size_t)row * 128 + l16 * 8) = o;
    }
}

// ---------------------------------------------------------------------------
// K12: out = relu([agg, H] @ W_up + b_up) via MFMA bf16.
// ---------------------------------------------------------------------------
__global__ __launch_bounds__(256) void k_final(
    const u16* __restrict__ aggb, const float* __restrict__ H,
    const u16* __restrict__ Wtu, const float* __restrict__ bup,
    float* __restrict__ out, int n)
{
    __shared__ __align__(16) u16 Asm[64 * 256];
    int tid = threadIdx.x;
    int r0blk = blockIdx.x * 64;

#pragma unroll
    for (int it = 0; it < 8; ++it) {
        int sidx = tid + it * 256;           // 64 rows x 32 slots
        int row = sidx >> 5, slot = sidx & 31;
        int gi = r0blk + row;
        uint4 w = make_uint4(0u, 0u, 0u, 0u);
        if (gi < n) {
            if (slot < 16) {
                w = *(const uint4*)(aggb + (size_t)gi * 128 + slot * 8);
            } else {
                const float4* p = (const float4*)(H + (size_t)gi * 128 + (slot - 16) * 8);
                float4 f0 = p[0], f1 = p[1];
                w.x = f2bf(f0.x) | ((u32)f2bf(f0.y) << 16);
                w.y = f2bf(f0.z) | ((u32)f2bf(f0.w) << 16);
                w.z = f2bf(f1.x) | ((u32)f2bf(f1.y) << 16);
                w.w = f2bf(f1.z) | ((u32)f2bf(f1.w) << 16);
            }
        }
        int grp = slot >> 3, sub = slot & 7;
        ((uint4*)Asm)[row * 32 + grp * 8 + (sub ^ (row & 7))] = w;
    }
    __syncthreads();

    int wv = tid >> 6, lane = tid & 63;
    int l15 = lane & 15, lg = lane >> 4;
    f32x4 acc[4][2] = {};
    const u16* Wb = Wtu + (size_t)(wv * 32) * 256;

#pragma unroll
    for (int ks = 0; ks < 8; ++ks) {
        bf16x8 bfr[2];
#pragma unroll
        for (int nt = 0; nt < 2; ++nt)
            bfr[nt] = *(const bf16x8*)(Wb + (size_t)(nt * 16 + l15) * 256 +
                                       ks * 32 + lg * 8);
        bf16x8 afr[4];
#pragma unroll
        for (int mt = 0; mt < 4; ++mt) {
            int row = mt * 16 + l15;
            int slot = ks * 4 + lg;
            int grp = slot >> 3, sub = slot & 7;
            afr[mt] = *(const bf16x8*)(Asm + row * 256 +
                                       (grp * 8 + (sub ^ (row & 7))) * 8);
        }
#pragma unroll
        for (int mt = 0; mt < 4; ++mt)
#pragma unroll
            for (int nt = 0; nt < 2; ++nt)
                acc[mt][nt] = __builtin_amdgcn_mfma_f32_16x16x32_bf16(
                    afr[mt], bfr[nt], acc[mt][nt], 0, 0, 0);
    }

#pragma unroll
    for (int mt = 0; mt < 4; ++mt)
#pragma unroll
        for (int r = 0; r < 4; ++r) {
            int gi = r0blk + mt * 16 + lg * 4 + r;
            if (gi >= n) continue;
#pragma unroll
            for (int nt = 0; nt < 2; ++nt) {
                int col = wv * 32 + nt * 16 + l15;
                float v = acc[mt][nt][r] + bup[col];
                out[(size_t)gi * 128 + col] = fmaxf(v, 0.f);
            }
        }
}

// ---------------------------------------------------------------------------
extern "C" void kernel_launch(void* const* d_in, const int* in_sizes, int n_in,
                              void* d_out, int out_size, void* d_ws,
                              size_t ws_size, hipStream_t stream)
{
    (void)n_in; (void)out_size; (void)ws_size;
    const float* H   = (const float*)d_in[0];
    const int*   ei  = (const int*)d_in[1];
    const float* ea  = (const float*)d_in[2];
    const float* W1  = (const float*)d_in[3];
    const float* W2  = (const float*)d_in[4];
    const float* We1 = (const float*)d_in[5];
    const float* be1 = (const float*)d_in[6];
    const float* We2 = (const float*)d_in[7];
    const float* be2 = (const float*)d_in[8];
    const float* g   = (const float*)d_in[9];
    const float* Wup = (const float*)d_in[10];
    const float* bup = (const float*)d_in[11];

    int n = in_sizes[0] / 128;
    int E = in_sizes[1] / 2;
    const int* src = ei;
    const int* dst = ei + E;
    float* out = (float*)d_out;

    char* wsp = (char*)d_ws;
    auto alloc = [&](size_t bytes) -> char* {
        char* p = wsp;
        wsp += (bytes + 255) & ~(size_t)255;
        return p;
    };
    float* ew     = (float*)alloc((size_t)E * 4);
    int*   tot    = (int*)alloc((size_t)n * 4);
    int*   rowptr = (int*)alloc((size_t)(n + 1) * 4);
    float* dinv   = (float*)alloc((size_t)n * 4);
    uint2* cva    = (uint2*)alloc((size_t)2 * E * 8);
    u16*   Wtc    = (u16*)alloc((size_t)256 * 128 * 2);
    u16*   Wtu    = (u16*)alloc((size_t)128 * 256 * 2);
    u16*   XXb    = (u16*)alloc((size_t)n * 256 * 2);
    u16*   Zb     = (u16*)alloc((size_t)n * 128 * 2);
    u16*   aggb   = (u16*)alloc((size_t)n * 128 * 2);
    // hb aliases [XXb | Zb | aggb]: NB*n*4 = 51.2e6 B == 25.6e6+12.8e6+12.8e6.
    // All three are dead until k_gemm1/k_spmm, which run after k_fill.
    int*   hb     = (int*)XXb;

    k_prep<<<256, 256, 0, stream>>>(W1, W2, Wup, Wtc, Wtu);
    k_edge<<<(E + 255) / 256, 256, 0, stream>>>(ea, We1, be1, We2, be2, ew, E);
    k_hist<<<NB, 1024, 0, stream>>>(src, dst, hb, E, n);
    k_rowsum<<<(n + 255) / 256, 256, 0, stream>>>(hb, tot, n);
    k_scan<<<1, 1024, 0, stream>>>(tot, rowptr, n);
    k_off<<<(n + 255) / 256, 256, 0, stream>>>(rowptr, hb, n);
    k_fill<<<NB, 1024, 0, stream>>>(src, dst, ew, hb, cva, E, n);
    k_deg<<<(n + 3) / 4, 256, 0, stream>>>(rowptr, cva, dinv, n);
    k_norm<<<(n + 3) / 4, 256, 0, stream>>>(rowptr, cva, dinv, n);
    k_gemm1<<<(n + 63) / 64, 256, 0, stream>>>(H, Wtc, XXb, n);
    // t = A @ X2 ; Z = gc*X1 + (1-gc)*t
    k_spmm<true><<<(n + 3) / 4, 256, 0, stream>>>(rowptr, cva, XXb, 256, 128,
                                                  XXb, Zb, g, n);
    // agg = A @ Z
    k_spmm<false><<<(n + 3) / 4, 256, 0, stream>>>(rowptr, cva, Zb, 128, 0,
                                                   nullptr, aggb, g, n);
    k_final<<<(n + 63) / 64, 256, 0, stream>>>(aggb, H, Wtu, bup, out, n);
}

// Round 7
// 325.395 us; speedup vs baseline: 2.2112x; 1.0420x over previous
//
#include <hip/hip_runtime.h>
#include <stdint.h>

typedef unsigned int u32;
typedef uint16_t u16;
typedef __attribute__((ext_vector_type(8))) short bf16x8;
typedef __attribute__((ext_vector_type(4))) float f32x4;

#define EPSV 1e-12f
#define NB 256           // histogram blocks (1 per CU)
#define BINS_H 25600     // hist bins/pass (u16 packed LDS, 2 passes)
#define BINS_F 12800     // fill bins/pass (int LDS, 4 passes)

__device__ __forceinline__ u16 f2bf(float f) {
    u32 u = __float_as_uint(f);
    return (u16)((u + 0x7fffu + ((u >> 16) & 1u)) >> 16);
}
__device__ __forceinline__ float bf2f(u32 s) { return __uint_as_float(s << 16); }

// ---------------------------------------------------------------------------
// K0: precompute transposed bf16 weights
// ---------------------------------------------------------------------------
__global__ __launch_bounds__(256) void k_prep(
    const float* __restrict__ W1, const float* __restrict__ W2,
    const float* __restrict__ Wup, u16* __restrict__ Wtc,
    u16* __restrict__ Wtu)
{
    int gid = blockIdx.x * 256 + threadIdx.x;
    if (gid < 32768) {
        int c = gid >> 7, k = gid & 127;
        float v = (c < 128) ? W1[k * 128 + c] : W2[k * 128 + (c - 128)];
        Wtc[gid] = f2bf(v);
    } else {
        int g = gid - 32768;      // c*256 + k
        int c = g >> 8, k = g & 255;
        Wtu[g] = f2bf(Wup[k * 128 + c]);
    }
}

// ---------------------------------------------------------------------------
// K1: edge MLP -> sigmoid weights (no atomics)
// ---------------------------------------------------------------------------
__global__ __launch_bounds__(256) void k_edge(
    const float* __restrict__ ea, const float* __restrict__ We1,
    const float* __restrict__ be1, const float* __restrict__ We2,
    const float* __restrict__ be2, float* __restrict__ ew, int E)
{
    __shared__ float w1t[32 * 16];
    __shared__ float b1s[32];
    __shared__ float w2s[32];
    __shared__ float b2s;
    int tid = threadIdx.x;
    for (int i = tid; i < 512; i += 256) {
        int k = i >> 5, j = i & 31;
        w1t[j * 16 + k] = We1[i];
    }
    if (tid < 32) { b1s[tid] = be1[tid]; w2s[tid] = We2[tid]; }
    if (tid == 0) b2s = be2[0];
    __syncthreads();

    int e = blockIdx.x * 256 + tid;
    if (e >= E) return;

    const float4* pa = (const float4*)(ea + (size_t)e * 16);
    float4 A0 = pa[0], A1 = pa[1], A2 = pa[2], A3 = pa[3];
    float av[16] = {A0.x, A0.y, A0.z, A0.w, A1.x, A1.y, A1.z, A1.w,
                    A2.x, A2.y, A2.z, A2.w, A3.x, A3.y, A3.z, A3.w};

    float acc = b2s;
#pragma unroll
    for (int j = 0; j < 32; ++j) {
        const float4* wr = (const float4*)(w1t + j * 16);
        float4 q0 = wr[0], q1 = wr[1], q2 = wr[2], q3 = wr[3];
        float s = b1s[j];
        s += av[0] * q0.x + av[1] * q0.y + av[2] * q0.z + av[3] * q0.w;
        s += av[4] * q1.x + av[5] * q1.y + av[6] * q1.z + av[7] * q1.w;
        s += av[8] * q2.x + av[9] * q2.y + av[10] * q2.z + av[11] * q2.w;
        s += av[12] * q3.x + av[13] * q3.y + av[14] * q3.z + av[15] * q3.w;
        acc += fmaxf(s, 0.f) * w2s[j];
    }
    ew[e] = 1.f / (1.f + __expf(-acc));
}

// ---------------------------------------------------------------------------
// K2: per-block LDS histograms of row ids (u16 LDS bins, int output).
//     hb32[b][r] = count of row r in block b's edge slice.
// ---------------------------------------------------------------------------
__global__ __launch_bounds__(1024) void k_hist(
    const int* __restrict__ src, const int* __restrict__ dst,
    int* __restrict__ hb32, int E, int n)
{
    __shared__ u32 h[BINS_H / 2];
    int b = blockIdx.x;
    int E2 = 2 * E;
    int per = (E2 + NB - 1) / NB;
    int lo_e = b * per, hi_e = min(E2, lo_e + per);
    int npass = (n + BINS_H - 1) / BINS_H;

    for (int pass = 0; pass < npass; ++pass) {
        int lo = pass * BINS_H, hi = min(n, lo + BINS_H);
        for (int i = threadIdx.x; i < BINS_H / 2; i += 1024) h[i] = 0;
        __syncthreads();
        for (int idx = lo_e + threadIdx.x; idx < hi_e; idx += 1024) {
            int r = (idx < E) ? src[idx] : dst[idx - E];
            if (r >= lo && r < hi) {
                int rr = r - lo;
                atomicAdd(&h[rr >> 1], 1u << ((rr & 1) * 16));
            }
        }
        __syncthreads();
        for (int i = threadIdx.x; i < hi - lo; i += 1024)
            hb32[(size_t)b * n + lo + i] =
                (int)((h[i >> 1] >> ((i & 1) * 16)) & 0xffffu);
        __syncthreads();
    }
}

// ---------------------------------------------------------------------------
// K3: tot[r] = sum_b hb32[b][r]
// ---------------------------------------------------------------------------
__global__ __launch_bounds__(256) void k_rowsum(
    const int* __restrict__ hb32, int* __restrict__ tot, int n)
{
    int r = blockIdx.x * 256 + threadIdx.x;
    if (r >= n) return;
    int s = 0;
#pragma unroll 8
    for (int b = 0; b < NB; ++b) s += hb32[(size_t)b * n + r];
    tot[r] = s;
}

// ---------------------------------------------------------------------------
// K4: single-block exclusive scan: tot -> rowptr
// ---------------------------------------------------------------------------
__global__ __launch_bounds__(1024) void k_scan(
    const int* __restrict__ tot, int* __restrict__ rowptr, int n)
{
    int tid = threadIdx.x, lane = tid & 63, w = tid >> 6;
    __shared__ int wsum[16];
    int running = 0;
    for (int base = 0; base < n; base += 1024) {
        int x = (base + tid < n) ? tot[base + tid] : 0;
        int v = x;
#pragma unroll
        for (int d = 1; d < 64; d <<= 1) {
            int t = __shfl_up(v, d);
            if (lane >= d) v += t;
        }
        if (lane == 63) wsum[w] = v;
        __syncthreads();
        if (w == 0) {
            int s = (lane < 16) ? wsum[lane] : 0;
#pragma unroll
            for (int d = 1; d < 16; d <<= 1) {
                int t = __shfl_up(s, d);
                if (lane >= d) s += t;
            }
            if (lane < 16) wsum[lane] = s;
        }
        __syncthreads();
        int waveoff = (w == 0) ? 0 : wsum[w - 1];
        if (base + tid < n) rowptr[base + tid] = running + waveoff + v - x;
        running += wsum[15];
        __syncthreads();
    }
    if (tid == 0) rowptr[n] = running;
}

// ---------------------------------------------------------------------------
// K5: hb32[b][r] <- rowptr[r] + prefix_{b'<b} hb32[b'][r]   (in place)
// ---------------------------------------------------------------------------
__global__ __launch_bounds__(256) void k_off(
    const int* __restrict__ rowptr, int* __restrict__ hb32, int n)
{
    int r = blockIdx.x * 256 + threadIdx.x;
    if (r >= n) return;
    int run = rowptr[r];
    for (int b = 0; b < NB; ++b) {
        int t = hb32[(size_t)b * n + r];
        hb32[(size_t)b * n + r] = run;
        run += t;
    }
}

// ---------------------------------------------------------------------------
// K6: fill CSR. Positions via LDS atomicAdd on preloaded per-block offsets.
//     cva[p] = {col, raw ew}
// ---------------------------------------------------------------------------
__global__ __launch_bounds__(1024) void k_fill(
    const int* __restrict__ src, const int* __restrict__ dst,
    const float* __restrict__ ew, const int* __restrict__ hb32,
    uint2* __restrict__ cva, int E, int n)
{
    __shared__ int hofs[BINS_F];
    int b = blockIdx.x;
    int E2 = 2 * E;
    int per = (E2 + NB - 1) / NB;
    int lo_e = b * per, hi_e = min(E2, lo_e + per);
    int npass = (n + BINS_F - 1) / BINS_F;

    for (int pass = 0; pass < npass; ++pass) {
        int lo = pass * BINS_F, hi = min(n, lo + BINS_F);
        for (int i = threadIdx.x; i < hi - lo; i += 1024)
            hofs[i] = hb32[(size_t)b * n + lo + i];
        __syncthreads();
        for (int idx = lo_e + threadIdx.x; idx < hi_e; idx += 1024) {
            int e = (idx < E) ? idx : idx - E;
            int r, c;
            if (idx < E) { r = src[e]; c = dst[e]; }
            else         { r = dst[e]; c = src[e]; }
            if (r >= lo && r < hi) {
                int pos = atomicAdd(&hofs[r - lo], 1);
                cva[pos] = make_uint2((u32)c, __float_as_uint(ew[e]));
            }
        }
        __syncthreads();
    }
}

// ---------------------------------------------------------------------------
// K7: deg (raw ew row sums) -> dinv (wave per row)
// ---------------------------------------------------------------------------
__global__ __launch_bounds__(256) void k_deg(
    const int* __restrict__ rowptr, const uint2* __restrict__ cva,
    float* __restrict__ dinv, int n)
{
    int lane = threadIdx.x & 63;
    int row = blockIdx.x * 4 + (threadIdx.x >> 6);
    if (row >= n) return;
    int s = rowptr[row], e = rowptr[row + 1];
    float sum = 0.f;
    for (int p = s + lane; p < e; p += 64) sum += __uint_as_float(cva[p].y);
#pragma unroll
    for (int d = 1; d < 64; d <<= 1) sum += __shfl_xor(sum, d);
    if (lane == 0) dinv[row] = rsqrtf(sum + EPSV);
}

// ---------------------------------------------------------------------------
// K9: XX = dinv ⊙ (H @ [W1|W2]) via MFMA bf16. 64 rows x 256 cols, 4 waves.
// ---------------------------------------------------------------------------
__global__ __launch_bounds__(256) void k_gemm1(
    const float* __restrict__ H, const u16* __restrict__ Wtc,
    const float* __restrict__ dinv, u16* __restrict__ XXb, int n)
{
    __shared__ __align__(16) u16 Asm[64 * 128];
    int tid = threadIdx.x;
    int r0blk = blockIdx.x * 64;

#pragma unroll
    for (int it = 0; it < 4; ++it) {
        int sidx = tid + it * 256;           // 64 rows x 16 slots
        int row = sidx >> 4, slot = sidx & 15;
        int gi = r0blk + row;
        float4 f0 = make_float4(0.f, 0.f, 0.f, 0.f), f1 = f0;
        if (gi < n) {
            const float4* p = (const float4*)(H + (size_t)gi * 128 + slot * 8);
            f0 = p[0]; f1 = p[1];
        }
        uint4 w;
        w.x = f2bf(f0.x) | ((u32)f2bf(f0.y) << 16);
        w.y = f2bf(f0.z) | ((u32)f2bf(f0.w) << 16);
        w.z = f2bf(f1.x) | ((u32)f2bf(f1.y) << 16);
        w.w = f2bf(f1.z) | ((u32)f2bf(f1.w) << 16);
        ((uint4*)Asm)[row * 16 + (slot ^ (row & 7))] = w;
    }
    __syncthreads();

    int wv = tid >> 6, lane = tid & 63;
    int l15 = lane & 15, lg = lane >> 4;
    f32x4 acc[4][4] = {};
    const u16* Wb = Wtc + (size_t)(wv * 64) * 128;

#pragma unroll
    for (int ks = 0; ks < 4; ++ks) {
        bf16x8 bfr[4];
#pragma unroll
        for (int nt = 0; nt < 4; ++nt)
            bfr[nt] = *(const bf16x8*)(Wb + (size_t)(nt * 16 + l15) * 128 +
                                       ks * 32 + lg * 8);
        bf16x8 afr[4];
#pragma unroll
        for (int mt = 0; mt < 4; ++mt) {
            int row = mt * 16 + l15;
            int slot = ks * 4 + lg;
            afr[mt] = *(const bf16x8*)(Asm + row * 128 + (slot ^ (row & 7)) * 8);
        }
#pragma unroll
        for (int mt = 0; mt < 4; ++mt)
#pragma unroll
            for (int nt = 0; nt < 4; ++nt)
                acc[mt][nt] = __builtin_amdgcn_mfma_f32_16x16x32_bf16(
                    afr[mt], bfr[nt], acc[mt][nt], 0, 0, 0);
    }

#pragma unroll
    for (int mt = 0; mt < 4; ++mt)
#pragma unroll
        for (int r = 0; r < 4; ++r) {
            int gi = r0blk + mt * 16 + lg * 4 + r;
            if (gi >= n) continue;
            float di = dinv[gi];
#pragma unroll
            for (int nt = 0; nt < 4; ++nt)
                XXb[(size_t)gi * 256 + wv * 64 + nt * 16 + l15] =
                    f2bf(acc[mt][nt][r] * di);
        }
}

// ---------------------------------------------------------------------------
// K10: 128-col SpMM with raw weights, quarter-wave gather, 4-deep pipeline.
//   MIX: out = gc * Xm[row][0:128] + (1-gc) * dinv[row]^2 * (Ar @ Xg)[row]
//  !MIX: out = (Ar @ Xg)[row]
// ---------------------------------------------------------------------------
template <bool MIX>
__global__ __launch_bounds__(256) void k_spmm(
    const int* __restrict__ rowptr, const uint2* __restrict__ cva,
    const u16* __restrict__ Xg, int gstride, int goff,
    const u16* __restrict__ Xm, u16* __restrict__ outb,
    const float* __restrict__ gp, const float* __restrict__ dinv, int n)
{
    int lane = threadIdx.x & 63;
    int q = lane >> 4, l16 = lane & 15;
    int row = blockIdx.x * 4 + (threadIdx.x >> 6);
    if (row >= n) return;
    int s = rowptr[row], e = rowptr[row + 1];
    float a[8] = {0.f, 0.f, 0.f, 0.f, 0.f, 0.f, 0.f, 0.f};

#define GATHER(DD, WW, JJ)                                                   \
    {                                                                        \
        int cj = __shfl(c, (JJ));                                            \
        WW = __shfl(w, (JJ));                                                \
        DD = *(const uint4*)(Xg + (size_t)cj * gstride + goff + l16 * 8);    \
    }
#define ACC(DD, WW)                                                          \
    {                                                                        \
        a[0] += WW * bf2f(DD.x & 0xffffu);                                   \
        a[1] += WW * bf2f(DD.x >> 16);                                       \
        a[2] += WW * bf2f(DD.y & 0xffffu);                                   \
        a[3] += WW * bf2f(DD.y >> 16);                                       \
        a[4] += WW * bf2f(DD.z & 0xffffu);                                   \
        a[5] += WW * bf2f(DD.z >> 16);                                       \
        a[6] += WW * bf2f(DD.w & 0xffffu);                                   \
        a[7] += WW * bf2f(DD.w >> 16);                                       \
    }

    for (int base = s; base < e; base += 64) {
        int p = base + lane;
        int c = 0; float w = 0.f;
        if (p < e) { uint2 cv = cva[p]; c = (int)cv.x; w = __uint_as_float(cv.y); }
        int m = min(64, e - base);
        for (int j0 = 0; j0 < m; j0 += 16) {
            uint4 d0, d1, d2, d3;
            float w0, w1, w2, w3;
            GATHER(d0, w0, j0 + q)
            GATHER(d1, w1, j0 + 4 + q)
            GATHER(d2, w2, j0 + 8 + q)
            GATHER(d3, w3, j0 + 12 + q)
            ACC(d0, w0) ACC(d1, w1) ACC(d2, w2) ACC(d3, w3)
        }
    }
#undef GATHER
#undef ACC

#pragma unroll
    for (int k = 0; k < 8; ++k) {
        a[k] += __shfl_xor(a[k], 16);
        a[k] += __shfl_xor(a[k], 32);
    }
    if (q == 0) {
        if (MIX) {
            float gc = fminf(fmaxf(gp[0], 0.f), 1.f);
            float di = dinv[row];
            float sc = (1.f - gc) * di * di;
            uint4 x1 = *(const uint4*)(Xm + (size_t)row * 256 + l16 * 8);
            a[0] = gc * bf2f(x1.x & 0xffffu) + sc * a[0];
            a[1] = gc * bf2f(x1.x >> 16)     + sc * a[1];
            a[2] = gc * bf2f(x1.y & 0xffffu) + sc * a[2];
            a[3] = gc * bf2f(x1.y >> 16)     + sc * a[3];
            a[4] = gc * bf2f(x1.z & 0xffffu) + sc * a[4];
            a[5] = gc * bf2f(x1.z >> 16)     + sc * a[5];
            a[6] = gc * bf2f(x1.w & 0xffffu) + sc * a[6];
            a[7] = gc * bf2f(x1.w >> 16)     + sc * a[7];
        }
        uint4 o;
        o.x = f2bf(a[0]) | ((u32)f2bf(a[1]) << 16);
        o.y = f2bf(a[2]) | ((u32)f2bf(a[3]) << 16);
        o.z = f2bf(a[4]) | ((u32)f2bf(a[5]) << 16);
        o.w = f2bf(a[6]) | ((u32)f2bf(a[7]) << 16);
        *(uint4*)(outb + (size_t)row * 128 + l16 * 8) = o;
    }
}

// ---------------------------------------------------------------------------
// K12: out = relu([dinv⊙agg, H] @ W_up + b_up) via MFMA bf16.
// ---------------------------------------------------------------------------
__global__ __launch_bounds__(256) void k_final(
    const u16* __restrict__ aggb, const float* __restrict__ H,
    const u16* __restrict__ Wtu, const float* __restrict__ bup,
    const float* __restrict__ dinv, float* __restrict__ out, int n)
{
    __shared__ __align__(16) u16 Asm[64 * 256];
    int tid = threadIdx.x;
    int r0blk = blockIdx.x * 64;

#pragma unroll
    for (int it = 0; it < 8; ++it) {
        int sidx = tid + it * 256;           // 64 rows x 32 slots
        int row = sidx >> 5, slot = sidx & 31;
        int gi = r0blk + row;
        uint4 w = make_uint4(0u, 0u, 0u, 0u);
        if (gi < n) {
            if (slot < 16) {
                uint4 y = *(const uint4*)(aggb + (size_t)gi * 128 + slot * 8);
                float di = dinv[gi];
                u32 ww[4] = {y.x, y.y, y.z, y.w};
#pragma unroll
                for (int q2 = 0; q2 < 4; ++q2) {
                    float a0 = bf2f(ww[q2] & 0xffffu) * di;
                    float a1 = bf2f(ww[q2] >> 16) * di;
                    ww[q2] = f2bf(a0) | ((u32)f2bf(a1) << 16);
                }
                w = make_uint4(ww[0], ww[1], ww[2], ww[3]);
            } else {
                const float4* p = (const float4*)(H + (size_t)gi * 128 + (slot - 16) * 8);
                float4 f0 = p[0], f1 = p[1];
                w.x = f2bf(f0.x) | ((u32)f2bf(f0.y) << 16);
                w.y = f2bf(f0.z) | ((u32)f2bf(f0.w) << 16);
                w.z = f2bf(f1.x) | ((u32)f2bf(f1.y) << 16);
                w.w = f2bf(f1.z) | ((u32)f2bf(f1.w) << 16);
            }
        }
        int grp = slot >> 3, sub = slot & 7;
        ((uint4*)Asm)[row * 32 + grp * 8 + (sub ^ (row & 7))] = w;
    }
    __syncthreads();

    int wv = tid >> 6, lane = tid & 63;
    int l15 = lane & 15, lg = lane >> 4;
    f32x4 acc[4][2] = {};
    const u16* Wb = Wtu + (size_t)(wv * 32) * 256;

#pragma unroll
    for (int ks = 0; ks < 8; ++ks) {
        bf16x8 bfr[2];
#pragma unroll
        for (int nt = 0; nt < 2; ++nt)
            bfr[nt] = *(const bf16x8*)(Wb + (size_t)(nt * 16 + l15) * 256 +
                                       ks * 32 + lg * 8);
        bf16x8 afr[4];
#pragma unroll
        for (int mt = 0; mt < 4; ++mt) {
            int row = mt * 16 + l15;
            int slot = ks * 4 + lg;
            int grp = slot >> 3, sub = slot & 7;
            afr[mt] = *(const bf16x8*)(Asm + row * 256 +
                                       (grp * 8 + (sub ^ (row & 7))) * 8);
        }
#pragma unroll
        for (int mt = 0; mt < 4; ++mt)
#pragma unroll
            for (int nt = 0; nt < 2; ++nt)
                acc[mt][nt] = __builtin_amdgcn_mfma_f32_16x16x32_bf16(
                    afr[mt], bfr[nt], acc[mt][nt], 0, 0, 0);
    }

#pragma unroll
    for (int mt = 0; mt < 4; ++mt)
#pragma unroll
        for (int r = 0; r < 4; ++r) {
            int gi = r0blk + mt * 16 + lg * 4 + r;
            if (gi >= n) continue;
#pragma unroll
            for (int nt = 0; nt < 2; ++nt) {
                int col = wv * 32 + nt * 16 + l15;
                float v = acc[mt][nt][r] + bup[col];
                out[(size_t)gi * 128 + col] = fmaxf(v, 0.f);
            }
        }
}

// ---------------------------------------------------------------------------
extern "C" void kernel_launch(void* const* d_in, const int* in_sizes, int n_in,
                              void* d_out, int out_size, void* d_ws,
                              size_t ws_size, hipStream_t stream)
{
    (void)n_in; (void)out_size; (void)ws_size;
    const float* H   = (const float*)d_in[0];
    const int*   ei  = (const int*)d_in[1];
    const float* ea  = (const float*)d_in[2];
    const float* W1  = (const float*)d_in[3];
    const float* W2  = (const float*)d_in[4];
    const float* We1 = (const float*)d_in[5];
    const float* be1 = (const float*)d_in[6];
    const float* We2 = (const float*)d_in[7];
    const float* be2 = (const float*)d_in[8];
    const float* g   = (const float*)d_in[9];
    const float* Wup = (const float*)d_in[10];
    const float* bup = (const float*)d_in[11];

    int n = in_sizes[0] / 128;
    int E = in_sizes[1] / 2;
    const int* src = ei;
    const int* dst = ei + E;
    float* out = (float*)d_out;

    char* wsp = (char*)d_ws;
    auto alloc = [&](size_t bytes) -> char* {
        char* p = wsp;
        wsp += (bytes + 255) & ~(size_t)255;
        return p;
    };
    float* ew     = (float*)alloc((size_t)E * 4);
    int*   tot    = (int*)alloc((size_t)n * 4);
    int*   rowptr = (int*)alloc((size_t)(n + 1) * 4);
    float* dinv   = (float*)alloc((size_t)n * 4);
    uint2* cva    = (uint2*)alloc((size_t)2 * E * 8);
    u16*   Wtc    = (u16*)alloc((size_t)256 * 128 * 2);
    u16*   Wtu    = (u16*)alloc((size_t)128 * 256 * 2);
    u16*   XXb    = (u16*)alloc((size_t)n * 256 * 2);
    u16*   Zb     = (u16*)alloc((size_t)n * 128 * 2);
    u16*   aggb   = (u16*)alloc((size_t)n * 128 * 2);
    // hb32 (NB*n*4 = 51.2e6 B) aliases [XXb|Zb|aggb] (25.6e6+12.8e6+12.8e6,
    // contiguous: each size is a 256-multiple). Dead once k_fill completes;
    // XXb/Zb/aggb are only written after that. NOTHING aliases cva (12.8 MB
    // < hb32 — that mismatch caused R6's OOB fault).
    int*   hb32   = (int*)XXb;

    k_prep<<<256, 256, 0, stream>>>(W1, W2, Wup, Wtc, Wtu);
    k_edge<<<(E + 255) / 256, 256, 0, stream>>>(ea, We1, be1, We2, be2, ew, E);
    k_hist<<<NB, 1024, 0, stream>>>(src, dst, hb32, E, n);
    k_rowsum<<<(n + 255) / 256, 256, 0, stream>>>(hb32, tot, n);
    k_scan<<<1, 1024, 0, stream>>>(tot, rowptr, n);
    k_off<<<(n + 255) / 256, 256, 0, stream>>>(rowptr, hb32, n);
    k_fill<<<NB, 1024, 0, stream>>>(src, dst, ew, hb32, cva, E, n);
    k_deg<<<(n + 3) / 4, 256, 0, stream>>>(rowptr, cva, dinv, n);
    k_gemm1<<<(n + 63) / 64, 256, 0, stream>>>(H, Wtc, dinv, XXb, n);
    // u = Ar @ X2' ; Z' = gc*X1' + (1-gc)*dinv^2*u
    k_spmm<true><<<(n + 3) / 4, 256, 0, stream>>>(rowptr, cva, XXb, 256, 128,
                                                  XXb, Zb, g, dinv, n);
    // v = Ar @ Z'
    k_spmm<false><<<(n + 3) / 4, 256, 0, stream>>>(rowptr, cva, Zb, 128, 0,
                                                   nullptr, aggb, g, dinv, n);
    k_final<<<(n + 63) / 64, 256, 0, stream>>>(aggb, H, Wtu, bup, dinv, out, n);
}